// Round 4
// baseline (961.777 us; speedup 1.0000x reference)
//
#include <hip/hip_runtime.h>
#include <hip/hip_bf16.h>

typedef unsigned short u16;
typedef unsigned int u32;
typedef __bf16 bf16x8 __attribute__((ext_vector_type(8)));
typedef float f32x4 __attribute__((ext_vector_type(4)));

__device__ __forceinline__ float bf2f(u16 h) { return __uint_as_float(((u32)h) << 16); }
__device__ __forceinline__ u16 f2bf(float f) {
    u32 u = __float_as_uint(f);
    u32 r = u + 0x7FFFu + ((u >> 16) & 1u);   // round-to-nearest-even
    return (u16)(r >> 16);
}
__device__ __forceinline__ void unpack8(const u16* p, float* b) {
    uint4 v = *(const uint4*)p;
    b[0] = bf2f((u16)(v.x & 0xFFFF)); b[1] = bf2f((u16)(v.x >> 16));
    b[2] = bf2f((u16)(v.y & 0xFFFF)); b[3] = bf2f((u16)(v.y >> 16));
    b[4] = bf2f((u16)(v.z & 0xFFFF)); b[5] = bf2f((u16)(v.z >> 16));
    b[6] = bf2f((u16)(v.w & 0xFFFF)); b[7] = bf2f((u16)(v.w >> 16));
}
template<int BF16>
__device__ __forceinline__ float LD(const void* p, long i) {
    if constexpr (BF16) return bf2f(((const u16*)p)[i]);
    else return ((const float*)p)[i];
}

// -------- detector: flags[0]=1 if floats are bf16; flags[1]=1 if edge_index is int64 --------
__global__ void k_detect(const u32* __restrict__ x, const u32* __restrict__ ei, u32* __restrict__ flags) {
    if (threadIdx.x == 0 && blockIdx.x == 0) {
        int c = 0;
        for (int i = 0; i < 256; i++) {
            u32 e = (x[i] >> 7) & 0xFF;
            if (e >= 96 && e <= 160) c++;
        }
        flags[0] = (c >= 192) ? 1u : 0u;
        int z = 0;
        for (int i = 0; i < 64; i++) if (ei[2 * i + 1] == 0u) z++;
        flags[1] = (z >= 48) ? 1u : 0u;
    }
}

__global__ void k_init(u32* __restrict__ p, int n) {
    for (int i = blockIdx.x * blockDim.x + threadIdx.x; i < n; i += gridDim.x * blockDim.x)
        p[i] = 0u;
}

// -------- prep: transposed/padded bf16 weights --------
__global__ void k_prep(const void* __restrict__ w0src, const void* __restrict__ w1src,
                       u16* __restrict__ w0t, u16* __restrict__ w1t,
                       const u32* __restrict__ flags, int koff) {
    int bf = (int)flags[0];
    int tid = blockIdx.x * blockDim.x + threadIdx.x;
    int stride = gridDim.x * blockDim.x;
    for (int i = tid; i < 128 * 128; i += stride) {
        int c = i >> 7, kp = i & 127;
        float v = 0.f;
        if (kp < 96) {
            int k = kp + koff;
            v = bf ? bf2f(((const u16*)w0src)[k * 128 + c]) : ((const float*)w0src)[k * 128 + c];
        }
        w0t[(long)c * 128 + kp] = f2bf(v);
    }
    for (int i = tid; i < 96 * 128; i += stride) {
        int c = i >> 7, k = i & 127;
        float v = bf ? bf2f(((const u16*)w1src)[k * 96 + c]) : ((const float*)w1src)[k * 96 + c];
        w1t[(long)c * 128 + k] = f2bf(v);
    }
}

// -------- counting sort of edges by dst: hist -> scan -> copy(starts) -> scatter --------
__global__ void k_hist(const u32* __restrict__ ei, u32* __restrict__ hist,
                       const u32* __restrict__ flags, int nE, int N) {
    u32 i64f = flags[1];
    for (long e = blockIdx.x * blockDim.x + threadIdx.x; e < nE; e += (long)gridDim.x * blockDim.x) {
        int dst = i64f ? (int)ei[2 * ((long)nE + e)] : (int)ei[(long)nE + e];
        dst = min(max(dst, 0), N - 1);
        atomicAdd(&hist[dst], 1u);
    }
}

__global__ void k_scan(u32* __restrict__ hist, int n) {   // 1 block, in-place exclusive scan
    __shared__ u32 sums[256];
    __shared__ u32 offs[256];
    int tid = threadIdx.x;
    int chunk = (n + 255) / 256;
    int lo = tid * chunk, hi = min(lo + chunk, n);
    u32 s = 0;
    for (int i = lo; i < hi; i++) s += hist[i];
    sums[tid] = s;
    __syncthreads();
    if (tid == 0) {
        u32 r = 0;
        for (int i = 0; i < 256; i++) { offs[i] = r; r += sums[i]; }
    }
    __syncthreads();
    u32 r = offs[tid];
    for (int i = lo; i < hi; i++) { u32 v = hist[i]; hist[i] = r; r += v; }
}

__global__ void k_copy(const u32* __restrict__ src, u32* __restrict__ dst, int n, u32 tail) {
    int i = blockIdx.x * blockDim.x + threadIdx.x;
    if (i < n) dst[i] = src[i];
    if (i == 0) dst[n] = tail;
}

__global__ void k_scatter(const u32* __restrict__ ei, u32* __restrict__ cur,
                          u32* __restrict__ ssrc, u32* __restrict__ sdst,
                          const u32* __restrict__ flags, int nE, int N) {
    u32 i64f = flags[1];
    for (long e = blockIdx.x * blockDim.x + threadIdx.x; e < nE; e += (long)gridDim.x * blockDim.x) {
        int src, dst;
        if (i64f) { src = (int)ei[2 * e]; dst = (int)ei[2 * ((long)nE + e)]; }
        else      { src = (int)ei[e];     dst = (int)ei[(long)nE + e]; }
        src = min(max(src, 0), N - 1);
        dst = min(max(dst, 0), N - 1);
        u32 p = atomicAdd(&cur[dst], 1u);
        ssrc[p] = (u32)src;
        sdst[p] = (u32)dst;
    }
}

// -------- K1: delta = mlp_h(x)  (96 -> 64 relu -> 3), f32 out --------
template<int BF16>
__global__ void k_delta(const void* __restrict__ x,
                        const void* __restrict__ hw0, const void* __restrict__ hb0,
                        const void* __restrict__ hw1, const void* __restrict__ hb1,
                        float* __restrict__ delta, const u32* __restrict__ flags, int N)
{
    if (flags[0] != (u32)BF16) return;
    __shared__ float w0[96 * 64];
    __shared__ float b0[64];
    __shared__ float w1[64 * 3];
    __shared__ float b1[3];
    int tid = threadIdx.x;
    for (int i = tid; i < 96 * 64; i += 256) w0[i] = LD<BF16>(hw0, i);
    if (tid < 64) b0[tid] = LD<BF16>(hb0, tid);
    if (tid < 64 * 3) w1[tid] = LD<BF16>(hw1, tid);
    if (tid < 3) b1[tid] = LD<BF16>(hb1, tid);
    __syncthreads();
    int n = blockIdx.x * 256 + tid;
    if (n >= N) return;
    float acc[64];
#pragma unroll
    for (int j = 0; j < 64; j++) acc[j] = b0[j];
    if constexpr (BF16) {
        const u32* xr = (const u32*)x + (long)n * 48;
        for (int kk = 0; kk < 48; kk++) {
            u32 p = xr[kk];
            float a0 = bf2f((u16)(p & 0xFFFF));
            float a1 = bf2f((u16)(p >> 16));
            const float* wr0 = &w0[(2 * kk) * 64];
            const float* wr1 = &w0[(2 * kk + 1) * 64];
#pragma unroll
            for (int j = 0; j < 64; j++) acc[j] += a0 * wr0[j] + a1 * wr1[j];
        }
    } else {
        const float* xr = (const float*)x + (long)n * 96;
        for (int k = 0; k < 96; k++) {
            float a0 = xr[k];
            const float* wr = &w0[k * 64];
#pragma unroll
            for (int j = 0; j < 64; j++) acc[j] += a0 * wr[j];
        }
    }
    float d0 = b1[0], d1 = b1[1], d2 = b1[2];
#pragma unroll
    for (int j = 0; j < 64; j++) {
        float h = fmaxf(acc[j], 0.f);
        d0 += h * w1[j * 3 + 0];
        d1 += h * w1[j * 3 + 1];
        d2 += h * w1[j * 3 + 2];
    }
    delta[(long)n * 3 + 0] = d0; delta[(long)n * 3 + 1] = d1; delta[(long)n * 3 + 2] = d2;
}

// -------- K2: MFMA edge MLP, barrier-free per-wave tiles, ZERO-ATOMIC segment max --------
// Per-wave LDS slice (8 KB at wid*8192): ein [16][128] bf16 swizzled; h at +4096; f32 out overlay
// (stride 98 words). Sorted-by-dst edges: complete runs -> plain bf16 store to agg[dst];
// boundary runs -> plain store to pbuf[head/tail][tile]; k_fixup merges multi-tile dsts.
template<int BF16>
__global__ __launch_bounds__(256, 4)
void k_edge(const void* __restrict__ x, const void* __restrict__ pos,
            const u32* __restrict__ ssrc, const u32* __restrict__ sdst,
            const float* __restrict__ delta,
            const u16* __restrict__ w0t, const u16* __restrict__ w1t,
            const void* __restrict__ fw0, const void* __restrict__ fb0, const void* __restrict__ fb1,
            const u32* __restrict__ flags, u16* __restrict__ agg, u16* __restrict__ pbuf,
            int nE, int N)
{
    if (flags[0] != (u32)BF16) return;
    __shared__ __align__(16) char arena[32768];
    __shared__ float relS[4][64];    // [wid][row*4+c]
    __shared__ int dstS[4][16];
    __shared__ float b0s[128];
    __shared__ float b1s[96];
    __shared__ float w0rS[3 * 128];
    int tid = threadIdx.x;
    if (tid < 128) b0s[tid] = LD<BF16>(fb0, tid);
    if (tid < 96)  b1s[tid] = LD<BF16>(fb1, tid);
    for (int i = tid; i < 384; i += 256) w0rS[i] = LD<BF16>(fw0, i);   // fw0 rows 0..2 (rel part)
    __syncthreads();   // one-time staging only

    const int lane = tid & 63;
    const int wid  = tid >> 6;
    char* const abase = arena + wid * 8192;
    char* const hbase = abase + 4096;
    const int r16  = lane & 15;
    const int kgrp = lane >> 4;
    const int sw   = (r16 & 7) << 4;
    const int srow = lane >> 2;
    const int q    = lane & 3;
    const int ssw  = (srow & 7) << 4;
    const int ntile = (nE + 15) / 16;
    const size_t tailSlot = (size_t)ntile * 96;

    float b0v[8];
#pragma unroll
    for (int nt = 0; nt < 8; nt++) b0v[nt] = b0s[nt * 16 + r16];

    // ---- gather prefetch regs (per-wave depth-1 pipeline) ----
    uint4 pfx[4];                  // BF16 x-row regs (q<3)
    float4 pfxf[8];                // f32 x-row regs (q<3)
    u32 pfps[3], pfpd[3];          // bf16 pos bits (q==3)
    float pfpsf[3], pfpdf[3];      // f32 pos (q==3)
    float pfdl[3];
    int   pfdst = 0;
    u32 nsrc = 0u, ndst = 0u;

    auto issueGathers = [&](u32 src, u32 dst) {
        if (q == 3) {
            pfdst = (int)dst;
            if constexpr (BF16) {
                const u16* pp = (const u16*)pos;
#pragma unroll
                for (int c = 0; c < 3; c++) {
                    pfps[c] = pp[(size_t)src * 3 + c];
                    pfpd[c] = pp[(size_t)dst * 3 + c];
                }
            } else {
                const float* pp = (const float*)pos;
#pragma unroll
                for (int c = 0; c < 3; c++) {
                    pfpsf[c] = pp[(size_t)src * 3 + c];
                    pfpdf[c] = pp[(size_t)dst * 3 + c];
                }
            }
#pragma unroll
            for (int c = 0; c < 3; c++) pfdl[c] = delta[(size_t)dst * 3 + c];
        } else {
            if constexpr (BF16) {
                const uint4* xp = (const uint4*)((const u16*)x + (size_t)src * 96);
#pragma unroll
                for (int j = 0; j < 4; j++) pfx[j] = xp[q * 4 + j];
            } else {
                const float4* xp = (const float4*)((const float*)x + (size_t)src * 96);
#pragma unroll
                for (int j = 0; j < 8; j++) pfxf[j] = xp[q * 8 + j];
            }
        }
    };
    auto writeStage = [&]() {
        if (q == 3) {
            dstS[wid][srow] = pfdst;
            if constexpr (BF16) {
#pragma unroll
                for (int c = 0; c < 3; c++)
                    relS[wid][srow * 4 + c] = bf2f((u16)pfps[c]) - bf2f((u16)pfpd[c]) + pfdl[c];
            } else {
#pragma unroll
                for (int c = 0; c < 3; c++)
                    relS[wid][srow * 4 + c] = pfpsf[c] - pfpdf[c] + pfdl[c];
            }
        } else {
            if constexpr (BF16) {
#pragma unroll
                for (int j = 0; j < 4; j++) {
                    int c = q * 4 + j;
                    *(uint4*)(abase + srow * 256 + ((c * 16) ^ ssw)) = pfx[j];
                }
            } else {
#pragma unroll
                for (int j = 0; j < 4; j++) {
                    int c = q * 4 + j;
                    float4 v0 = pfxf[2 * j], v1 = pfxf[2 * j + 1];
                    u32 o0 = (u32)f2bf(v0.x) | ((u32)f2bf(v0.y) << 16);
                    u32 o1 = (u32)f2bf(v0.z) | ((u32)f2bf(v0.w) << 16);
                    u32 o2 = (u32)f2bf(v1.x) | ((u32)f2bf(v1.y) << 16);
                    u32 o3 = (u32)f2bf(v1.z) | ((u32)f2bf(v1.w) << 16);
                    *(uint4*)(abase + srow * 256 + ((c * 16) ^ ssw)) = make_uint4(o0, o1, o2, o3);
                }
            }
        }
    };

    const int stride = (int)gridDim.x * 4;
    int t = (int)blockIdx.x * 4 + wid;
    if (t < ntile) {
        long E = min((long)t * 16 + srow, (long)nE - 1);
        issueGathers(ssrc[E], sdst[E]);
        int tn = t + stride;
        if (tn < ntile) {
            long En = min((long)tn * 16 + srow, (long)nE - 1);
            nsrc = ssrc[En]; ndst = sdst[En];
        }
    }

    for (; t < ntile; t += stride) {
        asm volatile("" ::: "memory");   // keep B-fragment loads inside the loop
        writeStage();                    // regs (tile t) -> LDS (waits gather vmcnt)
        {   // issue gathers for t+stride; indices for t+2*stride
            int tn = t + stride;
            if (tn < ntile) {
                issueGathers(nsrc, ndst);
                int tn2 = tn + stride;
                if (tn2 < ntile) {
                    long E2 = min((long)tn2 * 16 + srow, (long)nE - 1);
                    nsrc = ssrc[E2]; ndst = sdst[E2];
                }
            }
        }
        // early: neighbor dsts for boundary-run classification (broadcast loads)
        int dprevV = -1, dnextV = -1;
        {
            long e0 = (long)t * 16;
            if (e0 > 0) dprevV = (int)sdst[e0 - 1];
            long e1 = e0 + 16;
            if (e1 < (long)nE) dnextV = (int)sdst[e1];
        }
        // ---- GEMM1: h = relu(ein @ W0 + b0), K=96 MFMA + rank-3 rel init in f32 ----
        float rl[4][3];
#pragma unroll
        for (int r = 0; r < 4; r++) {
            int row = kgrp * 4 + r;
            rl[r][0] = relS[wid][row * 4 + 0];
            rl[r][1] = relS[wid][row * 4 + 1];
            rl[r][2] = relS[wid][row * 4 + 2];
        }
        f32x4 acc[8];
#pragma unroll
        for (int nt = 0; nt < 8; nt++) {
            int col = nt * 16 + r16;
            float wr0 = w0rS[col], wr1 = w0rS[128 + col], wr2 = w0rS[256 + col];
#pragma unroll
            for (int r = 0; r < 4; r++)
                acc[nt][r] = rl[r][0] * wr0 + rl[r][1] * wr1 + rl[r][2] * wr2;
        }
        bf16x8 a0 = *(const bf16x8*)(abase + r16 * 256 + ((0   + kgrp * 16) ^ sw));
        bf16x8 a1 = *(const bf16x8*)(abase + r16 * 256 + ((64  + kgrp * 16) ^ sw));
        bf16x8 a2 = *(const bf16x8*)(abase + r16 * 256 + ((128 + kgrp * 16) ^ sw));
#pragma unroll
        for (int nt = 0; nt < 8; nt++) {
            const u16* wp = w0t + (long)(nt * 16 + r16) * 128 + kgrp * 8;
            acc[nt] = __builtin_amdgcn_mfma_f32_16x16x32_bf16(a0, *(const bf16x8*)(wp),      acc[nt], 0, 0, 0);
            acc[nt] = __builtin_amdgcn_mfma_f32_16x16x32_bf16(a1, *(const bf16x8*)(wp + 32), acc[nt], 0, 0, 0);
            acc[nt] = __builtin_amdgcn_mfma_f32_16x16x32_bf16(a2, *(const bf16x8*)(wp + 64), acc[nt], 0, 0, 0);
        }
#pragma unroll
        for (int nt = 0; nt < 8; nt++) {
            int col = nt * 16 + r16;
#pragma unroll
            for (int r = 0; r < 4; r++) {
                int row = kgrp * 4 + r;
                float hv = fmaxf(acc[nt][r] + b0v[nt], 0.f);
                *(u16*)(hbase + row * 256 + ((col * 2) ^ ((row & 7) << 4))) = f2bf(hv);
            }
        }
        // ---- GEMM2: e2 = h @ W1, K=128, N=96 ----
        bf16x8 h0 = *(const bf16x8*)(hbase + r16 * 256 + ((0   + kgrp * 16) ^ sw));
        bf16x8 h1 = *(const bf16x8*)(hbase + r16 * 256 + ((64  + kgrp * 16) ^ sw));
        bf16x8 h2 = *(const bf16x8*)(hbase + r16 * 256 + ((128 + kgrp * 16) ^ sw));
        bf16x8 h3 = *(const bf16x8*)(hbase + r16 * 256 + ((192 + kgrp * 16) ^ sw));
        f32x4 acc2[6];
#pragma unroll
        for (int nt = 0; nt < 6; nt++) {
#pragma unroll
            for (int r = 0; r < 4; r++) acc2[nt][r] = 0.f;
        }
#pragma unroll
        for (int nt = 0; nt < 6; nt++) {
            const u16* wp = w1t + (long)(nt * 16 + r16) * 128 + kgrp * 8;
            acc2[nt] = __builtin_amdgcn_mfma_f32_16x16x32_bf16(h0, *(const bf16x8*)(wp),      acc2[nt], 0, 0, 0);
            acc2[nt] = __builtin_amdgcn_mfma_f32_16x16x32_bf16(h1, *(const bf16x8*)(wp + 32), acc2[nt], 0, 0, 0);
            acc2[nt] = __builtin_amdgcn_mfma_f32_16x16x32_bf16(h2, *(const bf16x8*)(wp + 64), acc2[nt], 0, 0, 0);
            acc2[nt] = __builtin_amdgcn_mfma_f32_16x16x32_bf16(h3, *(const bf16x8*)(wp + 96), acc2[nt], 0, 0, 0);
        }
#pragma unroll
        for (int nt = 0; nt < 6; nt++) {
            int col = nt * 16 + r16;
#pragma unroll
            for (int r = 0; r < 4; r++) {
                int row = kgrp * 4 + r;
                *(float*)(abase + (row * 98 + col) * 4) = acc2[nt][r];
            }
        }
        // ---- run-scan: plain stores (complete runs -> agg; boundary runs -> pbuf) ----
        {
            int d0s = dstS[wid][0], d15s = dstS[wid][15];
            bool extL = (dprevV == d0s);
            bool extR = (dnextV == d15s);
#pragma unroll
            for (int p = 0; p < 2; p++) {
                int col = p * 64 + lane;
                if (p == 0 || lane < 32) {
                    float b1c = b1s[col];
                    int curd = dstS[wid][0];
                    int r0 = 0;
                    float m = *(const float*)(abase + col * 4);
#pragma unroll
                    for (int row = 1; row < 16; row++) {
                        float v = *(const float*)(abase + (row * 98 + col) * 4);
                        int d = dstS[wid][row];
                        if (d != curd) {
                            // finish run [r0,row-1]: r1<15 so only head-partial possible
                            if (r0 == 0 && extL) pbuf[(size_t)t * 96 + col] = f2bf(m);
                            else agg[(size_t)curd * 96 + col] = f2bf(m + b1c);
                            curd = d; r0 = row; m = v;
                        } else m = fmaxf(m, v);
                    }
                    // final run [r0,15]
                    bool pl = (r0 == 0) && extL;
                    if (pl || extR) {
                        size_t slot = (r0 == 0) ? 0 : tailSlot;
                        pbuf[slot + (size_t)t * 96 + col] = f2bf(m);
                    } else agg[(size_t)curd * 96 + col] = f2bf(m + b1c);
                }
            }
        }
    }
}

// -------- k_fixup: merge partials for dsts spanning multiple tiles --------
__global__ void k_fixup(const u32* __restrict__ dstStart, const u16* __restrict__ pbuf,
                        u16* __restrict__ agg, const void* __restrict__ fb1,
                        const u32* __restrict__ flags, int N, int nE) {
    int gid = blockIdx.x * 256 + threadIdx.x;
    if (gid >= N * 96) return;
    u32 d = (u32)gid / 96u;
    int col = gid - (int)(d * 96u);
    u32 s = dstStart[d], e = dstStart[d + 1];
    if (e <= s) return;
    int t0 = (int)(s >> 4), t1 = (int)((e - 1) >> 4);
    if (t0 == t1) return;   // fully handled in-tile
    int ntile = (nE + 15) / 16;
    const u16* pH = pbuf;
    const u16* pT = pbuf + (size_t)ntile * 96;
    float m = bf2f((((s & 15u) == 0u) ? pH : pT)[(size_t)t0 * 96 + col]);
    for (int tt = t0 + 1; tt <= t1; tt++)
        m = fmaxf(m, bf2f(pH[(size_t)tt * 96 + col]));
    float b1c = flags[0] ? bf2f(((const u16*)fb1)[col]) : ((const float*)fb1)[col];
    agg[(size_t)d * 96 + col] = f2bf(m + b1c);
}

// -------- K3: out = x + mlp_g(agg)  (96 -> 128 relu -> 96), MFMA, 64-node tiles --------
template<int BF16>
__global__ __launch_bounds__(256)
void k_node(const void* __restrict__ x, const u16* __restrict__ agg,
            const u16* __restrict__ w0tg, const u16* __restrict__ w1tg,
            const void* __restrict__ gb0, const void* __restrict__ gb1,
            void* __restrict__ out, const u32* __restrict__ flags, int N)
{
    if (flags[0] != (u32)BF16) return;
    __shared__ __align__(16) char arena[32768];
    __shared__ float b0s[128];
    __shared__ float b1s[96];
    int tid = threadIdx.x;
    if (tid < 128) b0s[tid] = LD<BF16>(gb0, tid);
    if (tid < 96)  b1s[tid] = LD<BF16>(gb1, tid);
    __syncthreads();

    const int lane = tid & 63;
    const int wid  = tid >> 6;
    const int mrow0 = wid * 16;
    const int arow = mrow0 + (lane & 15);
    const int kgrp = lane >> 4;
    const int srow = tid >> 2;
    const int q = tid & 3;
    const int ssw = (srow & 7) << 4;

    float b0v[8];
#pragma unroll
    for (int nt = 0; nt < 8; nt++) b0v[nt] = b0s[nt * 16 + (lane & 15)];

    auto outOff = [](int row, int col) {
        int j = row & 15, w2 = row >> 4;
        int base = (j < 8) ? (w2 * 4096 + j * 512) : (16384 + w2 * 4096 + (j - 8) * 512);
        return base + ((col ^ (((row >> 2) & 3) << 4)) << 2);
    };

    int ntile = (N + 63) / 64;
    for (int t = blockIdx.x; t < ntile; t += gridDim.x) {
        asm volatile("" ::: "memory");
        {   // stage: copy agg row (bf16) -> swizzled ein
            int n = t * 64 + srow;
            if (n < N) {
                const uint4* ar = (const uint4*)(agg + (size_t)n * 96);
#pragma unroll
                for (int j = 0; j < 3; j++) {
                    int c = q * 3 + j;
                    *(uint4*)(arena + srow * 256 + ((c * 16) ^ ssw)) = ar[c];
                }
            } else {
#pragma unroll
                for (int j = 0; j < 3; j++)
                    *(uint4*)(arena + srow * 256 + (((q * 3 + j) * 16) ^ ssw)) = make_uint4(0u, 0u, 0u, 0u);
            }
        }
        __syncthreads();
        // ---- GEMM1: h = relu(agg @ W0 + b0), K=96 ----
        int sw = (arow & 7) << 4;
        bf16x8 a0 = *(const bf16x8*)(arena + arow * 256 + ((0   + kgrp * 16) ^ sw));
        bf16x8 a1 = *(const bf16x8*)(arena + arow * 256 + ((64  + kgrp * 16) ^ sw));
        bf16x8 a2 = *(const bf16x8*)(arena + arow * 256 + ((128 + kgrp * 16) ^ sw));
        f32x4 acc[8];
#pragma unroll
        for (int nt = 0; nt < 8; nt++) {
#pragma unroll
            for (int r = 0; r < 4; r++) acc[nt][r] = 0.f;
        }
#pragma unroll
        for (int nt = 0; nt < 8; nt++) {
            const u16* wp = w0tg + (long)(nt * 16 + (lane & 15)) * 128 + kgrp * 8;
            acc[nt] = __builtin_amdgcn_mfma_f32_16x16x32_bf16(a0, *(const bf16x8*)(wp),      acc[nt], 0, 0, 0);
            acc[nt] = __builtin_amdgcn_mfma_f32_16x16x32_bf16(a1, *(const bf16x8*)(wp + 32), acc[nt], 0, 0, 0);
            acc[nt] = __builtin_amdgcn_mfma_f32_16x16x32_bf16(a2, *(const bf16x8*)(wp + 64), acc[nt], 0, 0, 0);
        }
#pragma unroll
        for (int nt = 0; nt < 8; nt++) {
            int col = nt * 16 + (lane & 15);
#pragma unroll
            for (int r = 0; r < 4; r++) {
                int row = mrow0 + kgrp * 4 + r;
                float hv = fmaxf(acc[nt][r] + b0v[nt], 0.f);
                *(u16*)(arena + 16384 + row * 256 + ((col * 2) ^ ((row & 7) << 4))) = f2bf(hv);
            }
        }
        // ---- GEMM2: e2 = h @ W1, K=128, N=96 ----
        bf16x8 h0 = *(const bf16x8*)(arena + 16384 + arow * 256 + ((0   + kgrp * 16) ^ sw));
        bf16x8 h1 = *(const bf16x8*)(arena + 16384 + arow * 256 + ((64  + kgrp * 16) ^ sw));
        bf16x8 h2 = *(const bf16x8*)(arena + 16384 + arow * 256 + ((128 + kgrp * 16) ^ sw));
        bf16x8 h3 = *(const bf16x8*)(arena + 16384 + arow * 256 + ((192 + kgrp * 16) ^ sw));
        f32x4 acc2[6];
#pragma unroll
        for (int nt = 0; nt < 6; nt++) {
#pragma unroll
            for (int r = 0; r < 4; r++) acc2[nt][r] = 0.f;
        }
#pragma unroll
        for (int nt = 0; nt < 6; nt++) {
            const u16* wp = w1tg + (long)(nt * 16 + (lane & 15)) * 128 + kgrp * 8;
            acc2[nt] = __builtin_amdgcn_mfma_f32_16x16x32_bf16(h0, *(const bf16x8*)(wp),      acc2[nt], 0, 0, 0);
            acc2[nt] = __builtin_amdgcn_mfma_f32_16x16x32_bf16(h1, *(const bf16x8*)(wp + 32), acc2[nt], 0, 0, 0);
            acc2[nt] = __builtin_amdgcn_mfma_f32_16x16x32_bf16(h2, *(const bf16x8*)(wp + 64), acc2[nt], 0, 0, 0);
            acc2[nt] = __builtin_amdgcn_mfma_f32_16x16x32_bf16(h3, *(const bf16x8*)(wp + 96), acc2[nt], 0, 0, 0);
        }
#pragma unroll
        for (int nt = 0; nt < 6; nt++) {
            int col = nt * 16 + (lane & 15);
#pragma unroll
            for (int r = 0; r < 4; r++) {
                int row = mrow0 + kgrp * 4 + r;
                *(float*)(arena + outOff(row, col)) = acc2[nt][r];
            }
        }
        __syncthreads();
        // ---- epilogue: out = x + e2 + b1 ----
        {
            int n = t * 64 + srow;
            if (n < N) {
                float v[24];
#pragma unroll
                for (int c = 0; c < 24; c++) v[c] = *(const float*)(arena + outOff(srow, q * 24 + c));
                if constexpr (BF16) {
                    u16* orow = (u16*)out + (size_t)n * 96 + q * 24;
#pragma unroll
                    for (int j = 0; j < 3; j++) {
                        float xv[8];
                        unpack8((const u16*)x + (size_t)n * 96 + q * 24 + j * 8, xv);
                        u32 o[4];
#pragma unroll
                        for (int c2 = 0; c2 < 4; c2++) {
                            int c = j * 8 + 2 * c2;
                            u16 lo = f2bf(xv[2 * c2]     + v[c]     + b1s[q * 24 + c]);
                            u16 hi = f2bf(xv[2 * c2 + 1] + v[c + 1] + b1s[q * 24 + c + 1]);
                            o[c2] = (u32)lo | ((u32)hi << 16);
                        }
                        *(uint4*)(orow + j * 8) = make_uint4(o[0], o[1], o[2], o[3]);
                    }
                } else {
                    const float* xr = (const float*)x + (size_t)n * 96 + q * 24;
                    float* orow = (float*)out + (size_t)n * 96 + q * 24;
#pragma unroll
                    for (int j = 0; j < 6; j++) {
                        float4 xv = ((const float4*)xr)[j];
                        float4 o;
                        o.x = xv.x + v[4 * j + 0] + b1s[q * 24 + 4 * j + 0];
                        o.y = xv.y + v[4 * j + 1] + b1s[q * 24 + 4 * j + 1];
                        o.z = xv.z + v[4 * j + 2] + b1s[q * 24 + 4 * j + 2];
                        o.w = xv.w + v[4 * j + 3] + b1s[q * 24 + 4 * j + 3];
                        ((float4*)orow)[j] = o;
                    }
                }
            }
        }
        __syncthreads();
    }
}

extern "C" void kernel_launch(void* const* d_in, const int* in_sizes, int n_in,
                              void* d_out, int out_size, void* d_ws, size_t ws_size,
                              hipStream_t stream) {
    const void* x   = d_in[0];
    const void* pos = d_in[1];
    const void* ei  = d_in[2];
    const void* hw0 = d_in[3];
    const void* hb0 = d_in[4];
    const void* hw1 = d_in[5];
    const void* hb1 = d_in[6];
    const void* fw0 = d_in[7];
    const void* fb0 = d_in[8];
    const void* fw1 = d_in[9];
    const void* fb1 = d_in[10];
    const void* gw0 = d_in[11];
    const void* gb0 = d_in[12];
    const void* gw1 = d_in[13];
    const void* gb1 = d_in[14];

    int N  = in_sizes[0] / 96;   // 50000
    int nE = in_sizes[2] / 2;    // 800000
    int ntileE = (nE + 15) / 16; // 50000

    // workspace layout (256B aligned), total ~36.4 MB
    size_t off = 0;
    auto alloc = [&](size_t bytes) { size_t o = off; off = (off + bytes + 255) & ~(size_t)255; return o; };
    u32*   flags    = (u32*)((char*)d_ws + alloc(256));
    float* delta    = (float*)((char*)d_ws + alloc((size_t)N * 3 * 4));
    u16*   w0t      = (u16*)((char*)d_ws + alloc(128 * 128 * 2));
    u16*   w1t      = (u16*)((char*)d_ws + alloc(96 * 128 * 2));
    u16*   w0tg     = (u16*)((char*)d_ws + alloc(128 * 128 * 2));
    u16*   w1tg     = (u16*)((char*)d_ws + alloc(96 * 128 * 2));
    u32*   binCur   = (u32*)((char*)d_ws + alloc((size_t)N * 4));
    u32*   dstStart = (u32*)((char*)d_ws + alloc((size_t)(N + 1) * 4));
    u16*   agg      = (u16*)((char*)d_ws + alloc((size_t)N * 96 * 2));
    u32*   ssrc     = (u32*)((char*)d_ws + alloc((size_t)nE * 4));
    u32*   sdst     = (u32*)((char*)d_ws + alloc((size_t)nE * 4));
    u16*   pbuf     = (u16*)((char*)d_ws + alloc((size_t)2 * ntileE * 96 * 2));

    k_detect<<<1, 64, 0, stream>>>((const u32*)x, (const u32*)ei, flags);
    k_init<<<1024, 256, 0, stream>>>((u32*)agg, N * 96 / 2);
    k_init<<<256, 256, 0, stream>>>(binCur, N);
    k_prep<<<64, 256, 0, stream>>>(fw0, fw1, w0t, w1t, flags, 3);
    k_prep<<<64, 256, 0, stream>>>(gw0, gw1, w0tg, w1tg, flags, 0);
    k_hist<<<1024, 256, 0, stream>>>((const u32*)ei, binCur, flags, nE, N);
    k_scan<<<1, 256, 0, stream>>>(binCur, N);
    k_copy<<<(N + 255) / 256, 256, 0, stream>>>(binCur, dstStart, N, (u32)nE);
    k_scatter<<<1024, 256, 0, stream>>>((const u32*)ei, binCur, ssrc, sdst, flags, nE, N);
    k_delta<1><<<(N + 255) / 256, 256, 0, stream>>>(x, hw0, hb0, hw1, hb1, delta, flags, N);
    k_delta<0><<<(N + 255) / 256, 256, 0, stream>>>(x, hw0, hb0, hw1, hb1, delta, flags, N);
    k_edge<1><<<1024, 256, 0, stream>>>(x, pos, ssrc, sdst, delta, w0t, w1t, fw0, fb0, fb1, flags, agg, pbuf, nE, N);
    k_edge<0><<<1024, 256, 0, stream>>>(x, pos, ssrc, sdst, delta, w0t, w1t, fw0, fb0, fb1, flags, agg, pbuf, nE, N);
    k_fixup<<<(N * 96 + 255) / 256, 256, 0, stream>>>(dstStart, pbuf, agg, fb1, flags, N, nE);
    int nodeGrid = (N + 63) / 64;
    k_node<1><<<nodeGrid, 256, 0, stream>>>(x, agg, w0tg, w1tg, gb0, gb1, d_out, flags, N);
    k_node<0><<<nodeGrid, 256, 0, stream>>>(x, agg, w0tg, w1tg, gb0, gb1, d_out, flags, N);
}

// Round 5
// 566.814 us; speedup vs baseline: 1.6968x; 1.6968x over previous
//
#include <hip/hip_runtime.h>
#include <hip/hip_bf16.h>

typedef unsigned short u16;
typedef unsigned int u32;
typedef __bf16 bf16x8 __attribute__((ext_vector_type(8)));
typedef float f32x4 __attribute__((ext_vector_type(4)));

__device__ __forceinline__ float bf2f(u16 h) { return __uint_as_float(((u32)h) << 16); }
__device__ __forceinline__ u16 f2bf(float f) {
    u32 u = __float_as_uint(f);
    u32 r = u + 0x7FFFu + ((u >> 16) & 1u);   // round-to-nearest-even
    return (u16)(r >> 16);
}
__device__ __forceinline__ void unpack8(const u16* p, float* b) {
    uint4 v = *(const uint4*)p;
    b[0] = bf2f((u16)(v.x & 0xFFFF)); b[1] = bf2f((u16)(v.x >> 16));
    b[2] = bf2f((u16)(v.y & 0xFFFF)); b[3] = bf2f((u16)(v.y >> 16));
    b[4] = bf2f((u16)(v.z & 0xFFFF)); b[5] = bf2f((u16)(v.z >> 16));
    b[6] = bf2f((u16)(v.w & 0xFFFF)); b[7] = bf2f((u16)(v.w >> 16));
}
template<int BF16>
__device__ __forceinline__ float LD(const void* p, long i) {
    if constexpr (BF16) return bf2f(((const u16*)p)[i]);
    else return ((const float*)p)[i];
}

// -------- detector: flags[0]=1 if floats are bf16; flags[1]=1 if edge_index is int64 --------
__global__ void k_detect(const u32* __restrict__ x, const u32* __restrict__ ei, u32* __restrict__ flags) {
    if (threadIdx.x == 0 && blockIdx.x == 0) {
        int c = 0;
        for (int i = 0; i < 256; i++) {
            u32 e = (x[i] >> 7) & 0xFF;
            if (e >= 96 && e <= 160) c++;
        }
        flags[0] = (c >= 192) ? 1u : 0u;
        int z = 0;
        for (int i = 0; i < 64; i++) if (ei[2 * i + 1] == 0u) z++;
        flags[1] = (z >= 48) ? 1u : 0u;
    }
}

__global__ void k_init(u32* __restrict__ p, int n) {
    for (int i = blockIdx.x * blockDim.x + threadIdx.x; i < n; i += gridDim.x * blockDim.x)
        p[i] = 0u;
}

// -------- prep: transposed/padded bf16 weights.  w0t[c][kp] (128x128), w1t[c][k] (96x128) --------
__global__ void k_prep(const void* __restrict__ w0src, const void* __restrict__ w1src,
                       u16* __restrict__ w0t, u16* __restrict__ w1t,
                       const u32* __restrict__ flags, int koff) {
    int bf = (int)flags[0];
    int tid = blockIdx.x * blockDim.x + threadIdx.x;
    int stride = gridDim.x * blockDim.x;
    for (int i = tid; i < 128 * 128; i += stride) {
        int c = i >> 7, kp = i & 127;
        float v = 0.f;
        if (kp < 96) {
            int k = kp + koff;
            v = bf ? bf2f(((const u16*)w0src)[k * 128 + c]) : ((const float*)w0src)[k * 128 + c];
        }
        w0t[(long)c * 128 + kp] = f2bf(v);
    }
    for (int i = tid; i < 96 * 128; i += stride) {
        int c = i >> 7, k = i & 127;
        float v = bf ? bf2f(((const u16*)w1src)[k * 96 + c]) : ((const float*)w1src)[k * 96 + c];
        w1t[(long)c * 128 + k] = f2bf(v);
    }
}

// -------- counting sort of edges by dst --------
__global__ void k_hist(const u32* __restrict__ ei, u32* __restrict__ hist,
                       const u32* __restrict__ flags, int nE, int N) {
    u32 i64f = flags[1];
    for (long e = blockIdx.x * blockDim.x + threadIdx.x; e < nE; e += (long)gridDim.x * blockDim.x) {
        int dst = i64f ? (int)ei[2 * ((long)nE + e)] : (int)ei[(long)nE + e];
        dst = min(max(dst, 0), N - 1);
        atomicAdd(&hist[dst], 1u);
    }
}

__global__ void k_scan(u32* __restrict__ hist, int n) {
    __shared__ u32 sums[256];
    __shared__ u32 offs[256];
    int tid = threadIdx.x;
    int chunk = (n + 255) / 256;
    int lo = tid * chunk, hi = min(lo + chunk, n);
    u32 s = 0;
    for (int i = lo; i < hi; i++) s += hist[i];
    sums[tid] = s;
    __syncthreads();
    if (tid == 0) {
        u32 r = 0;
        for (int i = 0; i < 256; i++) { offs[i] = r; r += sums[i]; }
    }
    __syncthreads();
    u32 r = offs[tid];
    for (int i = lo; i < hi; i++) { u32 v = hist[i]; hist[i] = r; r += v; }
}

__global__ void k_copy(const u32* __restrict__ src, u32* __restrict__ dst, int n, u32 tail) {
    int i = blockIdx.x * blockDim.x + threadIdx.x;
    if (i < n) dst[i] = src[i];
    if (i == 0) dst[n] = tail;
}

__global__ void k_scatter(const u32* __restrict__ ei, u32* __restrict__ cur,
                          u32* __restrict__ ssrc, u32* __restrict__ sdst,
                          const u32* __restrict__ flags, int nE, int N) {
    u32 i64f = flags[1];
    for (long e = blockIdx.x * blockDim.x + threadIdx.x; e < nE; e += (long)gridDim.x * blockDim.x) {
        int src, dst;
        if (i64f) { src = (int)ei[2 * e]; dst = (int)ei[2 * ((long)nE + e)]; }
        else      { src = (int)ei[e];     dst = (int)ei[(long)nE + e]; }
        src = min(max(src, 0), N - 1);
        dst = min(max(dst, 0), N - 1);
        u32 p = atomicAdd(&cur[dst], 1u);
        ssrc[p] = (u32)src;
        sdst[p] = (u32)dst;
    }
}

// -------- K1: pd = mlp_h(x) - pos  (96 -> 64 relu -> 3), f32x4 out --------
template<int BF16>
__global__ void k_delta(const void* __restrict__ x, const void* __restrict__ pos,
                        const void* __restrict__ hw0, const void* __restrict__ hb0,
                        const void* __restrict__ hw1, const void* __restrict__ hb1,
                        float4* __restrict__ pd4, const u32* __restrict__ flags, int N)
{
    if (flags[0] != (u32)BF16) return;
    __shared__ float w0[96 * 64];
    __shared__ float b0[64];
    __shared__ float w1[64 * 3];
    __shared__ float b1[3];
    int tid = threadIdx.x;
    for (int i = tid; i < 96 * 64; i += 256) w0[i] = LD<BF16>(hw0, i);
    if (tid < 64) b0[tid] = LD<BF16>(hb0, tid);
    if (tid < 64 * 3) w1[tid] = LD<BF16>(hw1, tid);
    if (tid < 3) b1[tid] = LD<BF16>(hb1, tid);
    __syncthreads();
    int n = blockIdx.x * 256 + tid;
    if (n >= N) return;
    float acc[64];
#pragma unroll
    for (int j = 0; j < 64; j++) acc[j] = b0[j];
    if constexpr (BF16) {
        const u32* xr = (const u32*)x + (long)n * 48;
        for (int kk = 0; kk < 48; kk++) {
            u32 p = xr[kk];
            float a0 = bf2f((u16)(p & 0xFFFF));
            float a1 = bf2f((u16)(p >> 16));
            const float* wr0 = &w0[(2 * kk) * 64];
            const float* wr1 = &w0[(2 * kk + 1) * 64];
#pragma unroll
            for (int j = 0; j < 64; j++) acc[j] += a0 * wr0[j] + a1 * wr1[j];
        }
    } else {
        const float* xr = (const float*)x + (long)n * 96;
        for (int k = 0; k < 96; k++) {
            float a0 = xr[k];
            const float* wr = &w0[k * 64];
#pragma unroll
            for (int j = 0; j < 64; j++) acc[j] += a0 * wr[j];
        }
    }
    float d0 = b1[0], d1 = b1[1], d2 = b1[2];
#pragma unroll
    for (int j = 0; j < 64; j++) {
        float h = fmaxf(acc[j], 0.f);
        d0 += h * w1[j * 3 + 0];
        d1 += h * w1[j * 3 + 1];
        d2 += h * w1[j * 3 + 2];
    }
    float p0 = LD<BF16>(pos, (long)n * 3 + 0);
    float p1 = LD<BF16>(pos, (long)n * 3 + 1);
    float p2 = LD<BF16>(pos, (long)n * 3 + 2);
    pd4[n] = make_float4(d0 - p0, d1 - p1, d2 - p2, 0.f);
}

// -------- KY: y = x @ fw0[3:99]  (N x 128, bf16, no bias/relu), MFMA 64-node tiles --------
template<int BF16>
__global__ __launch_bounds__(256)
void k_y(const void* __restrict__ x, const u16* __restrict__ w0t,
         u16* __restrict__ y, const u32* __restrict__ flags, int N)
{
    if (flags[0] != (u32)BF16) return;
    __shared__ __align__(16) char arena[16384];
    int tid = threadIdx.x;
    const int lane = tid & 63;
    const int wid  = tid >> 6;
    const int mrow0 = wid * 16;
    const int r16  = lane & 15;
    const int arow = mrow0 + r16;
    const int kgrp = lane >> 4;
    const int srow = tid >> 2;
    const int q = tid & 3;
    const int ssw = (srow & 7) << 4;

    int ntile = (N + 63) / 64;
    for (int t = blockIdx.x; t < ntile; t += gridDim.x) {
        {   // stage x rows (96 cols) -> swizzled arena bf16
            int n = t * 64 + srow;
            if (n < N) {
                if constexpr (BF16) {
                    const uint4* ar = (const uint4*)((const u16*)x + (size_t)n * 96);
#pragma unroll
                    for (int j = 0; j < 3; j++) {
                        int c = q * 3 + j;
                        *(uint4*)(arena + srow * 256 + ((c * 16) ^ ssw)) = ar[c];
                    }
                } else {
                    const float4* xp = (const float4*)((const float*)x + (size_t)n * 96);
#pragma unroll
                    for (int j = 0; j < 3; j++) {
                        int c = q * 3 + j;
                        float4 v0 = xp[2 * c], v1 = xp[2 * c + 1];
                        u32 o0 = (u32)f2bf(v0.x) | ((u32)f2bf(v0.y) << 16);
                        u32 o1 = (u32)f2bf(v0.z) | ((u32)f2bf(v0.w) << 16);
                        u32 o2 = (u32)f2bf(v1.x) | ((u32)f2bf(v1.y) << 16);
                        u32 o3 = (u32)f2bf(v1.z) | ((u32)f2bf(v1.w) << 16);
                        *(uint4*)(arena + srow * 256 + ((c * 16) ^ ssw)) = make_uint4(o0, o1, o2, o3);
                    }
                }
            } else {
#pragma unroll
                for (int j = 0; j < 3; j++)
                    *(uint4*)(arena + srow * 256 + (((q * 3 + j) * 16) ^ ssw)) = make_uint4(0u, 0u, 0u, 0u);
            }
        }
        __syncthreads();
        int sw = (arow & 7) << 4;
        bf16x8 a0 = *(const bf16x8*)(arena + arow * 256 + ((0   + kgrp * 16) ^ sw));
        bf16x8 a1 = *(const bf16x8*)(arena + arow * 256 + ((64  + kgrp * 16) ^ sw));
        bf16x8 a2 = *(const bf16x8*)(arena + arow * 256 + ((128 + kgrp * 16) ^ sw));
        f32x4 acc[8];
#pragma unroll
        for (int nt = 0; nt < 8; nt++) {
#pragma unroll
            for (int r = 0; r < 4; r++) acc[nt][r] = 0.f;
        }
#pragma unroll
        for (int nt = 0; nt < 8; nt++) {
            const u16* wp = w0t + (long)(nt * 16 + r16) * 128 + kgrp * 8;
            acc[nt] = __builtin_amdgcn_mfma_f32_16x16x32_bf16(a0, *(const bf16x8*)(wp),      acc[nt], 0, 0, 0);
            acc[nt] = __builtin_amdgcn_mfma_f32_16x16x32_bf16(a1, *(const bf16x8*)(wp + 32), acc[nt], 0, 0, 0);
            acc[nt] = __builtin_amdgcn_mfma_f32_16x16x32_bf16(a2, *(const bf16x8*)(wp + 64), acc[nt], 0, 0, 0);
        }
#pragma unroll
        for (int nt = 0; nt < 8; nt++) {
#pragma unroll
            for (int r = 0; r < 4; r++) {
                int n2 = t * 64 + mrow0 + kgrp * 4 + r;
                if (n2 < N) y[(size_t)n2 * 128 + nt * 16 + r16] = f2bf(acc[nt][r]);
            }
        }
        __syncthreads();
    }
}

// -------- K2: edge MLP, GEMM2-only MFMA; y-fragment register gather; LDS W1; zero atomics --------
// Per edge: h = relu(y[src] + rel . W0[0:3] + b0)  computed per-lane on its own A-fragment slice,
// then e2 = h @ W1 via 24 MFMA with W1 staged (swizzled) in LDS. Barrier-free per-wave 16-edge tiles,
// depth-1 pipelined gathers; run-scan -> agg/pbuf (plain stores) + k_fixup.
template<int BF16>
__global__ __launch_bounds__(256)
void k_edge(const u16* __restrict__ y, const void* __restrict__ pos,
            const float4* __restrict__ pd4,
            const u32* __restrict__ ssrc, const u32* __restrict__ sdst,
            const u16* __restrict__ w1t,
            const void* __restrict__ fw0, const void* __restrict__ fb0, const void* __restrict__ fb1,
            const u32* __restrict__ flags, u16* __restrict__ agg, u16* __restrict__ pbuf,
            int nE, int N)
{
    if (flags[0] != (u32)BF16) return;
    __shared__ __align__(16) u16 w1S[96 * 128];      // 24576 B, XOR-swizzled rows of 256 B
    __shared__ float4 w0rb[128];                     // {w0r0,w0r1,w0r2,b0} per col, 2048 B
    __shared__ float b1s[96];
    __shared__ float relS[4][64];                    // [wid][r16*4+c]
    __shared__ int dstS[4][16];
    __shared__ float outS[4][16 * 97];               // stride-97 f32 out, 24832 B
    int tid = threadIdx.x;
    for (int i = tid; i < 96 * 64; i += 256) {       // stage w1t -> swizzled LDS (u32 granularity)
        int col = i >> 6, kp = i & 63;
        u32 v = ((const u32*)w1t)[i];
        *(u32*)((char*)w1S + col * 256 + ((kp * 4) ^ ((col & 7) << 4))) = v;
    }
    if (tid < 128)
        w0rb[tid] = make_float4(LD<BF16>(fw0, tid), LD<BF16>(fw0, 128 + tid),
                                LD<BF16>(fw0, 256 + tid), LD<BF16>(fb0, tid));
    if (tid < 96) b1s[tid] = LD<BF16>(fb1, tid);
    __syncthreads();   // one-time staging only

    const int lane = tid & 63;
    const int wid  = tid >> 6;
    const int r16  = lane & 15;
    const int kgrp = lane >> 4;
    const int ntile = (nE + 15) / 16;
    const size_t tailSlot = (size_t)ntile * 96;
    float* const outSw = outS[wid];

    const int stride = (int)gridDim.x * 4;
    int t = (int)blockIdx.x * 4 + wid;

    // pipeline regs
    u32 cs = 0u, cd = 0u, ns = 0u, nd2 = 0u;
    uint4 G[4];                       // y fragments for tile t
    u16 prp[3]; float prpf[3];        // pos[src] for tile t (kgrp==3)
    float4 prpd = make_float4(0, 0, 0, 0);

    auto issueGather = [&](u32 src, u32 dst) {
        const u16* yp = y + (size_t)src * 128 + kgrp * 8;
#pragma unroll
        for (int f = 0; f < 4; f++) G[f] = *(const uint4*)(yp + f * 32);
        if (kgrp == 3) {
            if constexpr (BF16) {
                const u16* pp = (const u16*)pos;
#pragma unroll
                for (int c = 0; c < 3; c++) prp[c] = pp[(size_t)src * 3 + c];
            } else {
                const float* pp = (const float*)pos;
#pragma unroll
                for (int c = 0; c < 3; c++) prpf[c] = pp[(size_t)src * 3 + c];
            }
            prpd = pd4[dst];
        }
    };

    if (t < ntile) {
        long E = min((long)t * 16 + r16, (long)nE - 1);
        cs = ssrc[E]; cd = sdst[E];
        issueGather(cs, cd);
        int tn = t + stride;
        if (tn < ntile) {
            long En = min((long)tn * 16 + r16, (long)nE - 1);
            ns = ssrc[En]; nd2 = sdst[En];
        }
    }

    for (; t < ntile; t += stride) {
        asm volatile("" ::: "memory");
        // stage rel/dst for tile t (kgrp3 lanes; intra-wave DS in-order)
        if (kgrp == 3) {
            dstS[wid][r16] = (int)cd;
            float p0, p1, p2;
            if constexpr (BF16) { p0 = bf2f(prp[0]); p1 = bf2f(prp[1]); p2 = bf2f(prp[2]); }
            else                { p0 = prpf[0]; p1 = prpf[1]; p2 = prpf[2]; }
            relS[wid][r16 * 4 + 0] = p0 + prpd.x;
            relS[wid][r16 * 4 + 1] = p1 + prpd.y;
            relS[wid][r16 * 4 + 2] = p2 + prpd.z;
        }
        // neighbor dsts for boundary-run classification
        int dprevV = -1, dnextV = -1;
        {
            long e0 = (long)t * 16;
            if (e0 > 0) dprevV = (int)sdst[e0 - 1];
            if (e0 + 16 < (long)nE) dnextV = (int)sdst[e0 + 16];
        }
        float rl0 = relS[wid][r16 * 4 + 0];
        float rl1 = relS[wid][r16 * 4 + 1];
        float rl2 = relS[wid][r16 * 4 + 2];
        // ---- h fragments: relu(y + rel.w0r + b0), lane-local on its A-fragment slice ----
        bf16x8 hf[4];
#pragma unroll
        for (int f = 0; f < 4; f++) {
            u32 hw[4];
#pragma unroll
            for (int jj = 0; jj < 4; jj++) {
                int c0 = f * 32 + kgrp * 8 + 2 * jj;
                float4 wb0 = w0rb[c0];
                float4 wb1 = w0rb[c0 + 1];
                u32 pw = ((const u32*)&G[f])[jj];
                float y0 = bf2f((u16)(pw & 0xFFFF));
                float y1 = bf2f((u16)(pw >> 16));
                float h0 = fmaxf(y0 + rl0 * wb0.x + rl1 * wb0.y + rl2 * wb0.z + wb0.w, 0.f);
                float h1 = fmaxf(y1 + rl0 * wb1.x + rl1 * wb1.y + rl2 * wb1.z + wb1.w, 0.f);
                hw[jj] = (u32)f2bf(h0) | ((u32)f2bf(h1) << 16);
            }
            uint4 hv = make_uint4(hw[0], hw[1], hw[2], hw[3]);
            hf[f] = *(const bf16x8*)&hv;
        }
        // ---- G is dead: issue next tile's gathers + indices (depth-1 pipeline) ----
        u32 cs2 = ns, cd2 = nd2;
        {
            int tn = t + stride;
            if (tn < ntile) {
                issueGather(cs2, cd2);
                int tn2 = tn + stride;
                if (tn2 < ntile) {
                    long E2 = min((long)tn2 * 16 + r16, (long)nE - 1);
                    ns = ssrc[E2]; nd2 = sdst[E2];
                }
            }
        }
        // ---- GEMM2: e2 = h @ W1 (K=128, N=96), W1 from swizzled LDS ----
        f32x4 acc2[6];
#pragma unroll
        for (int nt = 0; nt < 6; nt++) {
#pragma unroll
            for (int r = 0; r < 4; r++) acc2[nt][r] = 0.f;
        }
#pragma unroll
        for (int nt = 0; nt < 6; nt++) {
            int colr = nt * 16 + r16;
            const char* wb = (const char*)w1S + colr * 256;
            int csw = (colr & 7) << 4;
            acc2[nt] = __builtin_amdgcn_mfma_f32_16x16x32_bf16(hf[0], *(const bf16x8*)(wb + ((kgrp * 16)       ^ csw)), acc2[nt], 0, 0, 0);
            acc2[nt] = __builtin_amdgcn_mfma_f32_16x16x32_bf16(hf[1], *(const bf16x8*)(wb + ((kgrp * 16 + 64)  ^ csw)), acc2[nt], 0, 0, 0);
            acc2[nt] = __builtin_amdgcn_mfma_f32_16x16x32_bf16(hf[2], *(const bf16x8*)(wb + ((kgrp * 16 + 128) ^ csw)), acc2[nt], 0, 0, 0);
            acc2[nt] = __builtin_amdgcn_mfma_f32_16x16x32_bf16(hf[3], *(const bf16x8*)(wb + ((kgrp * 16 + 192) ^ csw)), acc2[nt], 0, 0, 0);
        }
        // out (f32) -> wave-local stride-97 overlay
#pragma unroll
        for (int nt = 0; nt < 6; nt++) {
            int col = nt * 16 + r16;
#pragma unroll
            for (int r = 0; r < 4; r++) {
                int row = kgrp * 4 + r;
                outSw[row * 97 + col] = acc2[nt][r];
            }
        }
        // ---- run-scan: plain stores (complete runs -> agg; boundary -> pbuf) ----
        {
            int d0s = dstS[wid][0], d15s = dstS[wid][15];
            bool extL = (dprevV == d0s);
            bool extR = (dnextV == d15s);
#pragma unroll
            for (int p = 0; p < 2; p++) {
                int col = p * 64 + lane;
                if (p == 0 || lane < 32) {
                    float b1c = b1s[col];
                    int curd = d0s;
                    int r0 = 0;
                    float m = outSw[col];
#pragma unroll
                    for (int row = 1; row < 16; row++) {
                        float v = outSw[row * 97 + col];
                        int d = dstS[wid][row];
                        if (d != curd) {
                            if (r0 == 0 && extL) pbuf[(size_t)t * 96 + col] = f2bf(m);
                            else agg[(size_t)curd * 96 + col] = f2bf(m + b1c);
                            curd = d; r0 = row; m = v;
                        } else m = fmaxf(m, v);
                    }
                    bool pl = (r0 == 0) && extL;
                    if (pl || extR) {
                        size_t slot = (r0 == 0) ? 0 : tailSlot;
                        pbuf[slot + (size_t)t * 96 + col] = f2bf(m);
                    } else agg[(size_t)curd * 96 + col] = f2bf(m + b1c);
                }
            }
        }
        cs = cs2; cd = cd2;
    }
}

// -------- k_fixup: merge partials for dsts spanning multiple tiles --------
__global__ void k_fixup(const u32* __restrict__ dstStart, const u16* __restrict__ pbuf,
                        u16* __restrict__ agg, const void* __restrict__ fb1,
                        const u32* __restrict__ flags, int N, int nE) {
    int gid = blockIdx.x * 256 + threadIdx.x;
    if (gid >= N * 96) return;
    u32 d = (u32)gid / 96u;
    int col = gid - (int)(d * 96u);
    u32 s = dstStart[d], e = dstStart[d + 1];
    if (e <= s) return;
    int t0 = (int)(s >> 4), t1 = (int)((e - 1) >> 4);
    if (t0 == t1) return;
    int ntile = (nE + 15) / 16;
    const u16* pH = pbuf;
    const u16* pT = pbuf + (size_t)ntile * 96;
    float m = bf2f((((s & 15u) == 0u) ? pH : pT)[(size_t)t0 * 96 + col]);
    for (int tt = t0 + 1; tt <= t1; tt++)
        m = fmaxf(m, bf2f(pH[(size_t)tt * 96 + col]));
    float b1c = flags[0] ? bf2f(((const u16*)fb1)[col]) : ((const float*)fb1)[col];
    agg[(size_t)d * 96 + col] = f2bf(m + b1c);
}

// -------- K3: out = x + mlp_g(agg)  (96 -> 128 relu -> 96), MFMA, 64-node tiles --------
template<int BF16>
__global__ __launch_bounds__(256)
void k_node(const void* __restrict__ x, const u16* __restrict__ agg,
            const u16* __restrict__ w0tg, const u16* __restrict__ w1tg,
            const void* __restrict__ gb0, const void* __restrict__ gb1,
            void* __restrict__ out, const u32* __restrict__ flags, int N)
{
    if (flags[0] != (u32)BF16) return;
    __shared__ __align__(16) char arena[32768];
    __shared__ float b0s[128];
    __shared__ float b1s[96];
    int tid = threadIdx.x;
    if (tid < 128) b0s[tid] = LD<BF16>(gb0, tid);
    if (tid < 96)  b1s[tid] = LD<BF16>(gb1, tid);
    __syncthreads();

    const int lane = tid & 63;
    const int wid  = tid >> 6;
    const int mrow0 = wid * 16;
    const int arow = mrow0 + (lane & 15);
    const int kgrp = lane >> 4;
    const int srow = tid >> 2;
    const int q = tid & 3;
    const int ssw = (srow & 7) << 4;

    float b0v[8];
#pragma unroll
    for (int nt = 0; nt < 8; nt++) b0v[nt] = b0s[nt * 16 + (lane & 15)];

    auto outOff = [](int row, int col) {
        int j = row & 15, w2 = row >> 4;
        int base = (j < 8) ? (w2 * 4096 + j * 512) : (16384 + w2 * 4096 + (j - 8) * 512);
        return base + ((col ^ (((row >> 2) & 3) << 4)) << 2);
    };

    int ntile = (N + 63) / 64;
    for (int t = blockIdx.x; t < ntile; t += gridDim.x) {
        asm volatile("" ::: "memory");
        {
            int n = t * 64 + srow;
            if (n < N) {
                const uint4* ar = (const uint4*)(agg + (size_t)n * 96);
#pragma unroll
                for (int j = 0; j < 3; j++) {
                    int c = q * 3 + j;
                    *(uint4*)(arena + srow * 256 + ((c * 16) ^ ssw)) = ar[c];
                }
            } else {
#pragma unroll
                for (int j = 0; j < 3; j++)
                    *(uint4*)(arena + srow * 256 + (((q * 3 + j) * 16) ^ ssw)) = make_uint4(0u, 0u, 0u, 0u);
            }
        }
        __syncthreads();
        int sw = (arow & 7) << 4;
        bf16x8 a0 = *(const bf16x8*)(arena + arow * 256 + ((0   + kgrp * 16) ^ sw));
        bf16x8 a1 = *(const bf16x8*)(arena + arow * 256 + ((64  + kgrp * 16) ^ sw));
        bf16x8 a2 = *(const bf16x8*)(arena + arow * 256 + ((128 + kgrp * 16) ^ sw));
        f32x4 acc[8];
#pragma unroll
        for (int nt = 0; nt < 8; nt++) {
#pragma unroll
            for (int r = 0; r < 4; r++) acc[nt][r] = 0.f;
        }
#pragma unroll
        for (int nt = 0; nt < 8; nt++) {
            const u16* wp = w0tg + (long)(nt * 16 + (lane & 15)) * 128 + kgrp * 8;
            acc[nt] = __builtin_amdgcn_mfma_f32_16x16x32_bf16(a0, *(const bf16x8*)(wp),      acc[nt], 0, 0, 0);
            acc[nt] = __builtin_amdgcn_mfma_f32_16x16x32_bf16(a1, *(const bf16x8*)(wp + 32), acc[nt], 0, 0, 0);
            acc[nt] = __builtin_amdgcn_mfma_f32_16x16x32_bf16(a2, *(const bf16x8*)(wp + 64), acc[nt], 0, 0, 0);
        }
#pragma unroll
        for (int nt = 0; nt < 8; nt++) {
            int col = nt * 16 + (lane & 15);
#pragma unroll
            for (int r = 0; r < 4; r++) {
                int row = mrow0 + kgrp * 4 + r;
                float hv = fmaxf(acc[nt][r] + b0v[nt], 0.f);
                *(u16*)(arena + 16384 + row * 256 + ((col * 2) ^ ((row & 7) << 4))) = f2bf(hv);
            }
        }
        bf16x8 h0 = *(const bf16x8*)(arena + 16384 + arow * 256 + ((0   + kgrp * 16) ^ sw));
        bf16x8 h1 = *(const bf16x8*)(arena + 16384 + arow * 256 + ((64  + kgrp * 16) ^ sw));
        bf16x8 h2 = *(const bf16x8*)(arena + 16384 + arow * 256 + ((128 + kgrp * 16) ^ sw));
        bf16x8 h3 = *(const bf16x8*)(arena + 16384 + arow * 256 + ((192 + kgrp * 16) ^ sw));
        f32x4 acc2[6];
#pragma unroll
        for (int nt = 0; nt < 6; nt++) {
#pragma unroll
            for (int r = 0; r < 4; r++) acc2[nt][r] = 0.f;
        }
#pragma unroll
        for (int nt = 0; nt < 6; nt++) {
            const u16* wp = w1tg + (long)(nt * 16 + (lane & 15)) * 128 + kgrp * 8;
            acc2[nt] = __builtin_amdgcn_mfma_f32_16x16x32_bf16(h0, *(const bf16x8*)(wp),      acc2[nt], 0, 0, 0);
            acc2[nt] = __builtin_amdgcn_mfma_f32_16x16x32_bf16(h1, *(const bf16x8*)(wp + 32), acc2[nt], 0, 0, 0);
            acc2[nt] = __builtin_amdgcn_mfma_f32_16x16x32_bf16(h2, *(const bf16x8*)(wp + 64), acc2[nt], 0, 0, 0);
            acc2[nt] = __builtin_amdgcn_mfma_f32_16x16x32_bf16(h3, *(const bf16x8*)(wp + 96), acc2[nt], 0, 0, 0);
        }
#pragma unroll
        for (int nt = 0; nt < 6; nt++) {
            int col = nt * 16 + (lane & 15);
#pragma unroll
            for (int r = 0; r < 4; r++) {
                int row = mrow0 + kgrp * 4 + r;
                *(float*)(arena + outOff(row, col)) = acc2[nt][r];
            }
        }
        __syncthreads();
        {
            int n = t * 64 + srow;
            if (n < N) {
                float v[24];
#pragma unroll
                for (int c = 0; c < 24; c++) v[c] = *(const float*)(arena + outOff(srow, q * 24 + c));
                if constexpr (BF16) {
                    u16* orow = (u16*)out + (size_t)n * 96 + q * 24;
#pragma unroll
                    for (int j = 0; j < 3; j++) {
                        float xv[8];
                        unpack8((const u16*)x + (size_t)n * 96 + q * 24 + j * 8, xv);
                        u32 o[4];
#pragma unroll
                        for (int c2 = 0; c2 < 4; c2++) {
                            int c = j * 8 + 2 * c2;
                            u16 lo = f2bf(xv[2 * c2]     + v[c]     + b1s[q * 24 + c]);
                            u16 hi = f2bf(xv[2 * c2 + 1] + v[c + 1] + b1s[q * 24 + c + 1]);
                            o[c2] = (u32)lo | ((u32)hi << 16);
                        }
                        *(uint4*)(orow + j * 8) = make_uint4(o[0], o[1], o[2], o[3]);
                    }
                } else {
                    const float* xr = (const float*)x + (size_t)n * 96 + q * 24;
                    float* orow = (float*)out + (size_t)n * 96 + q * 24;
#pragma unroll
                    for (int j = 0; j < 6; j++) {
                        float4 xv = ((const float4*)xr)[j];
                        float4 o;
                        o.x = xv.x + v[4 * j + 0] + b1s[q * 24 + 4 * j + 0];
                        o.y = xv.y + v[4 * j + 1] + b1s[q * 24 + 4 * j + 1];
                        o.z = xv.z + v[4 * j + 2] + b1s[q * 24 + 4 * j + 2];
                        o.w = xv.w + v[4 * j + 3] + b1s[q * 24 + 4 * j + 3];
                        ((float4*)orow)[j] = o;
                    }
                }
            }
        }
        __syncthreads();
    }
}

extern "C" void kernel_launch(void* const* d_in, const int* in_sizes, int n_in,
                              void* d_out, int out_size, void* d_ws, size_t ws_size,
                              hipStream_t stream) {
    const void* x   = d_in[0];
    const void* pos = d_in[1];
    const void* ei  = d_in[2];
    const void* hw0 = d_in[3];
    const void* hb0 = d_in[4];
    const void* hw1 = d_in[5];
    const void* hb1 = d_in[6];
    const void* fw0 = d_in[7];
    const void* fb0 = d_in[8];
    const void* fw1 = d_in[9];
    const void* fb1 = d_in[10];
    const void* gw0 = d_in[11];
    const void* gb0 = d_in[12];
    const void* gw1 = d_in[13];
    const void* gb1 = d_in[14];

    int N  = in_sizes[0] / 96;   // 50000
    int nE = in_sizes[2] / 2;    // 800000
    int ntileE = (nE + 15) / 16; // 50000

    // workspace layout (256B aligned), total ~50 MB
    size_t off = 0;
    auto alloc = [&](size_t bytes) { size_t o = off; off = (off + bytes + 255) & ~(size_t)255; return o; };
    u32*    flags    = (u32*)((char*)d_ws + alloc(256));
    float4* pd4      = (float4*)((char*)d_ws + alloc((size_t)N * 16));
    u16*    w0t      = (u16*)((char*)d_ws + alloc(128 * 128 * 2));
    u16*    w1t      = (u16*)((char*)d_ws + alloc(96 * 128 * 2));
    u16*    w0tg     = (u16*)((char*)d_ws + alloc(128 * 128 * 2));
    u16*    w1tg     = (u16*)((char*)d_ws + alloc(96 * 128 * 2));
    u32*    binCur   = (u32*)((char*)d_ws + alloc((size_t)N * 4));
    u32*    dstStart = (u32*)((char*)d_ws + alloc((size_t)(N + 1) * 4));
    u16*    agg      = (u16*)((char*)d_ws + alloc((size_t)N * 96 * 2));
    u32*    ssrc     = (u32*)((char*)d_ws + alloc((size_t)nE * 4));
    u32*    sdst     = (u32*)((char*)d_ws + alloc((size_t)nE * 4));
    u16*    pbuf     = (u16*)((char*)d_ws + alloc((size_t)2 * ntileE * 96 * 2));
    u16*    ybuf     = (u16*)((char*)d_ws + alloc((size_t)N * 128 * 2));

    k_detect<<<1, 64, 0, stream>>>((const u32*)x, (const u32*)ei, flags);
    k_init<<<1024, 256, 0, stream>>>((u32*)agg, N * 96 / 2);
    k_init<<<256, 256, 0, stream>>>(binCur, N);
    k_prep<<<64, 256, 0, stream>>>(fw0, fw1, w0t, w1t, flags, 3);
    k_prep<<<64, 256, 0, stream>>>(gw0, gw1, w0tg, w1tg, flags, 0);
    k_hist<<<1024, 256, 0, stream>>>((const u32*)ei, binCur, flags, nE, N);
    k_scan<<<1, 256, 0, stream>>>(binCur, N);
    k_copy<<<(N + 255) / 256, 256, 0, stream>>>(binCur, dstStart, N, (u32)nE);
    k_scatter<<<1024, 256, 0, stream>>>((const u32*)ei, binCur, ssrc, sdst, flags, nE, N);
    k_delta<1><<<(N + 255) / 256, 256, 0, stream>>>(x, pos, hw0, hb0, hw1, hb1, pd4, flags, N);
    k_delta<0><<<(N + 255) / 256, 256, 0, stream>>>(x, pos, hw0, hb0, hw1, hb1, pd4, flags, N);
    int yGrid = (N + 63) / 64;
    k_y<1><<<yGrid, 256, 0, stream>>>(x, w0t, ybuf, flags, N);
    k_y<0><<<yGrid, 256, 0, stream>>>(x, w0t, ybuf, flags, N);
    k_edge<1><<<768, 256, 0, stream>>>(ybuf, pos, pd4, ssrc, sdst, w1t, fw0, fb0, fb1, flags, agg, pbuf, nE, N);
    k_edge<0><<<768, 256, 0, stream>>>(ybuf, pos, pd4, ssrc, sdst, w1t, fw0, fb0, fb1, flags, agg, pbuf, nE, N);
    k_fixup<<<(N * 96 + 255) / 256, 256, 0, stream>>>(dstStart, pbuf, agg, fb1, flags, N, nE);
    int nodeGrid = (N + 63) / 64;
    k_node<1><<<nodeGrid, 256, 0, stream>>>(x, agg, w0tg, w1tg, gb0, gb1, d_out, flags, N);
    k_node<0><<<nodeGrid, 256, 0, stream>>>(x, agg, w0tg, w1tg, gb0, gb1, d_out, flags, N);
}

// Round 6
// 545.235 us; speedup vs baseline: 1.7640x; 1.0396x over previous
//
#include <hip/hip_runtime.h>
#include <hip/hip_bf16.h>

typedef unsigned short u16;
typedef unsigned int u32;
typedef __bf16 bf16x8 __attribute__((ext_vector_type(8)));
typedef float f32x4 __attribute__((ext_vector_type(4)));

__device__ __forceinline__ float bf2f(u16 h) { return __uint_as_float(((u32)h) << 16); }
__device__ __forceinline__ u16 f2bf(float f) {
    u32 u = __float_as_uint(f);
    u32 r = u + 0x7FFFu + ((u >> 16) & 1u);   // round-to-nearest-even
    return (u16)(r >> 16);
}
__device__ __forceinline__ void unpack8(const u16* p, float* b) {
    uint4 v = *(const uint4*)p;
    b[0] = bf2f((u16)(v.x & 0xFFFF)); b[1] = bf2f((u16)(v.x >> 16));
    b[2] = bf2f((u16)(v.y & 0xFFFF)); b[3] = bf2f((u16)(v.y >> 16));
    b[4] = bf2f((u16)(v.z & 0xFFFF)); b[5] = bf2f((u16)(v.z >> 16));
    b[6] = bf2f((u16)(v.w & 0xFFFF)); b[7] = bf2f((u16)(v.w >> 16));
}
template<int BF16>
__device__ __forceinline__ float LD(const void* p, long i) {
    if constexpr (BF16) return bf2f(((const u16*)p)[i]);
    else return ((const float*)p)[i];
}

// -------- detector: flags[0]=1 if floats are bf16; flags[1]=1 if edge_index is int64 --------
__global__ void k_detect(const u32* __restrict__ x, const u32* __restrict__ ei, u32* __restrict__ flags) {
    if (threadIdx.x == 0 && blockIdx.x == 0) {
        int c = 0;
        for (int i = 0; i < 256; i++) {
            u32 e = (x[i] >> 7) & 0xFF;
            if (e >= 96 && e <= 160) c++;
        }
        flags[0] = (c >= 192) ? 1u : 0u;
        int z = 0;
        for (int i = 0; i < 64; i++) if (ei[2 * i + 1] == 0u) z++;
        flags[1] = (z >= 48) ? 1u : 0u;
    }
}

__global__ void k_initall(u32* __restrict__ a, int na, u32* __restrict__ b, int nb) {
    int stride = gridDim.x * blockDim.x;
    int g = blockIdx.x * blockDim.x + threadIdx.x;
    for (int i = g; i < na; i += stride) a[i] = 0u;
    for (int i = g; i < nb; i += stride) b[i] = 0u;
}

// -------- prep: transposed/padded bf16 weights.  w0t[c][kp] (128x128), w1t[c][k] (96x128) --------
__global__ void k_prep(const void* __restrict__ w0src, const void* __restrict__ w1src,
                       u16* __restrict__ w0t, u16* __restrict__ w1t,
                       const u32* __restrict__ flags, int koff) {
    int bf = (int)flags[0];
    int tid = blockIdx.x * blockDim.x + threadIdx.x;
    int stride = gridDim.x * blockDim.x;
    for (int i = tid; i < 128 * 128; i += stride) {
        int c = i >> 7, kp = i & 127;
        float v = 0.f;
        if (kp < 96) {
            int k = kp + koff;
            v = bf ? bf2f(((const u16*)w0src)[k * 128 + c]) : ((const float*)w0src)[k * 128 + c];
        }
        w0t[(long)c * 128 + kp] = f2bf(v);
    }
    for (int i = tid; i < 96 * 128; i += stride) {
        int c = i >> 7, k = i & 127;
        float v = bf ? bf2f(((const u16*)w1src)[k * 96 + c]) : ((const float*)w1src)[k * 96 + c];
        w1t[(long)c * 128 + k] = f2bf(v);
    }
}

// -------- counting sort of edges by dst --------
__global__ void k_hist(const u32* __restrict__ ei, u32* __restrict__ hist,
                       const u32* __restrict__ flags, int nE, int N) {
    u32 i64f = flags[1];
    for (long e = blockIdx.x * blockDim.x + threadIdx.x; e < nE; e += (long)gridDim.x * blockDim.x) {
        int dst = i64f ? (int)ei[2 * ((long)nE + e)] : (int)ei[(long)nE + e];
        dst = min(max(dst, 0), N - 1);
        atomicAdd(&hist[dst], 1u);
    }
}

// 1 block x 1024 threads: in-place exclusive scan of hist; also writes dstart[] (+ tail)
__global__ void k_scan(u32* __restrict__ hist, u32* __restrict__ dstart, int n, u32 total) {
    __shared__ u32 sums[1024];
    __shared__ u32 offs[1024];
    int tid = threadIdx.x;
    int chunk = (n + 1023) / 1024;
    int lo = tid * chunk, hi = min(lo + chunk, n);
    u32 s = 0;
    for (int i = lo; i < hi; i++) s += hist[i];
    sums[tid] = s;
    __syncthreads();
    if (tid == 0) {
        u32 r = 0;
        for (int i = 0; i < 1024; i++) { offs[i] = r; r += sums[i]; }
    }
    __syncthreads();
    u32 r = offs[tid];
    for (int i = lo; i < hi; i++) { u32 v = hist[i]; hist[i] = r; dstart[i] = r; r += v; }
    if (tid == 0) dstart[n] = total;
}

__global__ void k_scatter(const u32* __restrict__ ei, u32* __restrict__ cur,
                          u32* __restrict__ ssrc, u32* __restrict__ sdst,
                          const u32* __restrict__ flags, int nE, int N) {
    u32 i64f = flags[1];
    for (long e = blockIdx.x * blockDim.x + threadIdx.x; e < nE; e += (long)gridDim.x * blockDim.x) {
        int src, dst;
        if (i64f) { src = (int)ei[2 * e]; dst = (int)ei[2 * ((long)nE + e)]; }
        else      { src = (int)ei[e];     dst = (int)ei[(long)nE + e]; }
        src = min(max(src, 0), N - 1);
        dst = min(max(dst, 0), N - 1);
        u32 p = atomicAdd(&cur[dst], 1u);
        ssrc[p] = (u32)src;
        sdst[p] = (u32)dst;
    }
}

// -------- K1: pd = mlp_h(x) - pos  (96 -> 64 relu -> 3), f32x4 out --------
template<int BF16>
__global__ void k_delta(const void* __restrict__ x, const void* __restrict__ pos,
                        const void* __restrict__ hw0, const void* __restrict__ hb0,
                        const void* __restrict__ hw1, const void* __restrict__ hb1,
                        float4* __restrict__ pd4, const u32* __restrict__ flags, int N)
{
    if (flags[0] != (u32)BF16) return;
    __shared__ float w0[96 * 64];
    __shared__ float b0[64];
    __shared__ float w1[64 * 3];
    __shared__ float b1[3];
    int tid = threadIdx.x;
    for (int i = tid; i < 96 * 64; i += 256) w0[i] = LD<BF16>(hw0, i);
    if (tid < 64) b0[tid] = LD<BF16>(hb0, tid);
    if (tid < 64 * 3) w1[tid] = LD<BF16>(hw1, tid);
    if (tid < 3) b1[tid] = LD<BF16>(hb1, tid);
    __syncthreads();
    int n = blockIdx.x * 256 + tid;
    if (n >= N) return;
    float acc[64];
#pragma unroll
    for (int j = 0; j < 64; j++) acc[j] = b0[j];
    if constexpr (BF16) {
        const u32* xr = (const u32*)x + (long)n * 48;
        for (int kk = 0; kk < 48; kk++) {
            u32 p = xr[kk];
            float a0 = bf2f((u16)(p & 0xFFFF));
            float a1 = bf2f((u16)(p >> 16));
            const float* wr0 = &w0[(2 * kk) * 64];
            const float* wr1 = &w0[(2 * kk + 1) * 64];
#pragma unroll
            for (int j = 0; j < 64; j++) acc[j] += a0 * wr0[j] + a1 * wr1[j];
        }
    } else {
        const float* xr = (const float*)x + (long)n * 96;
        for (int k = 0; k < 96; k++) {
            float a0 = xr[k];
            const float* wr = &w0[k * 64];
#pragma unroll
            for (int j = 0; j < 64; j++) acc[j] += a0 * wr[j];
        }
    }
    float d0 = b1[0], d1 = b1[1], d2 = b1[2];
#pragma unroll
    for (int j = 0; j < 64; j++) {
        float h = fmaxf(acc[j], 0.f);
        d0 += h * w1[j * 3 + 0];
        d1 += h * w1[j * 3 + 1];
        d2 += h * w1[j * 3 + 2];
    }
    float p0 = LD<BF16>(pos, (long)n * 3 + 0);
    float p1 = LD<BF16>(pos, (long)n * 3 + 1);
    float p2 = LD<BF16>(pos, (long)n * 3 + 2);
    pd4[n] = make_float4(d0 - p0, d1 - p1, d2 - p2, 0.f);
}

// -------- KY: y = x @ fw0[3:99]  (N x 128, bf16, no bias/relu), MFMA 64-node tiles --------
template<int BF16>
__global__ __launch_bounds__(256)
void k_y(const void* __restrict__ x, const u16* __restrict__ w0t,
         u16* __restrict__ y, const u32* __restrict__ flags, int N)
{
    if (flags[0] != (u32)BF16) return;
    __shared__ __align__(16) char arena[16384];
    int tid = threadIdx.x;
    const int lane = tid & 63;
    const int wid  = tid >> 6;
    const int mrow0 = wid * 16;
    const int r16  = lane & 15;
    const int arow = mrow0 + r16;
    const int kgrp = lane >> 4;
    const int srow = tid >> 2;
    const int q = tid & 3;
    const int ssw = (srow & 7) << 4;

    int ntile = (N + 63) / 64;
    for (int t = blockIdx.x; t < ntile; t += gridDim.x) {
        {   // stage x rows (96 cols) -> swizzled arena bf16
            int n = t * 64 + srow;
            if (n < N) {
                if constexpr (BF16) {
                    const uint4* ar = (const uint4*)((const u16*)x + (size_t)n * 96);
#pragma unroll
                    for (int j = 0; j < 3; j++) {
                        int c = q * 3 + j;
                        *(uint4*)(arena + srow * 256 + ((c * 16) ^ ssw)) = ar[c];
                    }
                } else {
                    const float4* xp = (const float4*)((const float*)x + (size_t)n * 96);
#pragma unroll
                    for (int j = 0; j < 3; j++) {
                        int c = q * 3 + j;
                        float4 v0 = xp[2 * c], v1 = xp[2 * c + 1];
                        u32 o0 = (u32)f2bf(v0.x) | ((u32)f2bf(v0.y) << 16);
                        u32 o1 = (u32)f2bf(v0.z) | ((u32)f2bf(v0.w) << 16);
                        u32 o2 = (u32)f2bf(v1.x) | ((u32)f2bf(v1.y) << 16);
                        u32 o3 = (u32)f2bf(v1.z) | ((u32)f2bf(v1.w) << 16);
                        *(uint4*)(arena + srow * 256 + ((c * 16) ^ ssw)) = make_uint4(o0, o1, o2, o3);
                    }
                }
            } else {
#pragma unroll
                for (int j = 0; j < 3; j++)
                    *(uint4*)(arena + srow * 256 + (((q * 3 + j) * 16) ^ ssw)) = make_uint4(0u, 0u, 0u, 0u);
            }
        }
        __syncthreads();
        int sw = (arow & 7) << 4;
        bf16x8 a0 = *(const bf16x8*)(arena + arow * 256 + ((0   + kgrp * 16) ^ sw));
        bf16x8 a1 = *(const bf16x8*)(arena + arow * 256 + ((64  + kgrp * 16) ^ sw));
        bf16x8 a2 = *(const bf16x8*)(arena + arow * 256 + ((128 + kgrp * 16) ^ sw));
        f32x4 acc[8];
#pragma unroll
        for (int nt = 0; nt < 8; nt++) {
#pragma unroll
            for (int r = 0; r < 4; r++) acc[nt][r] = 0.f;
        }
#pragma unroll
        for (int nt = 0; nt < 8; nt++) {
            const u16* wp = w0t + (long)(nt * 16 + r16) * 128 + kgrp * 8;
            acc[nt] = __builtin_amdgcn_mfma_f32_16x16x32_bf16(a0, *(const bf16x8*)(wp),      acc[nt], 0, 0, 0);
            acc[nt] = __builtin_amdgcn_mfma_f32_16x16x32_bf16(a1, *(const bf16x8*)(wp + 32), acc[nt], 0, 0, 0);
            acc[nt] = __builtin_amdgcn_mfma_f32_16x16x32_bf16(a2, *(const bf16x8*)(wp + 64), acc[nt], 0, 0, 0);
        }
#pragma unroll
        for (int nt = 0; nt < 8; nt++) {
#pragma unroll
            for (int r = 0; r < 4; r++) {
                int n2 = t * 64 + mrow0 + kgrp * 4 + r;
                if (n2 < N) y[(size_t)n2 * 128 + nt * 16 + r16] = f2bf(acc[nt][r]);
            }
        }
        __syncthreads();
    }
}

// -------- K2: edge MLP, GEMM2-only MFMA; y-fragment register gather; LDS W1; zero atomics --------
// bf16 out overlay (stride 98) -> total LDS 40832 B -> 4 blocks/CU.
template<int BF16>
__global__ __launch_bounds__(256)
void k_edge(const u16* __restrict__ y, const void* __restrict__ pos,
            const float4* __restrict__ pd4,
            const u32* __restrict__ ssrc, const u32* __restrict__ sdst,
            const u16* __restrict__ w1t,
            const void* __restrict__ fw0, const void* __restrict__ fb0, const void* __restrict__ fb1,
            const u32* __restrict__ flags, u16* __restrict__ agg, u16* __restrict__ pbuf,
            int nE, int N)
{
    if (flags[0] != (u32)BF16) return;
    __shared__ __align__(16) u16 w1S[96 * 128];      // 24576 B, XOR-swizzled rows of 256 B
    __shared__ float4 w0rb[128];                     // {w0r0,w0r1,w0r2,b0} per col, 2048 B
    __shared__ float b1s[96];                        // 384 B
    __shared__ float relS[4][64];                    // 1024 B
    __shared__ int dstS[4][16];                      // 256 B
    __shared__ __align__(16) u16 outS[4][16 * 98];   // bf16 out, stride 98, 12544 B
    int tid = threadIdx.x;
    for (int i = tid; i < 96 * 64; i += 256) {       // stage w1t -> swizzled LDS (u32 granularity)
        int col = i >> 6, kp = i & 63;
        u32 v = ((const u32*)w1t)[i];
        *(u32*)((char*)w1S + col * 256 + ((kp * 4) ^ ((col & 7) << 4))) = v;
    }
    if (tid < 128)
        w0rb[tid] = make_float4(LD<BF16>(fw0, tid), LD<BF16>(fw0, 128 + tid),
                                LD<BF16>(fw0, 256 + tid), LD<BF16>(fb0, tid));
    if (tid < 96) b1s[tid] = LD<BF16>(fb1, tid);
    __syncthreads();   // one-time staging only

    const int lane = tid & 63;
    const int wid  = tid >> 6;
    const int r16  = lane & 15;
    const int kgrp = lane >> 4;
    const int ntile = (nE + 15) / 16;
    const size_t tailSlot = (size_t)ntile * 96;
    u16* const outSw = outS[wid];

    const int stride = (int)gridDim.x * 4;
    int t = (int)blockIdx.x * 4 + wid;

    // pipeline regs
    u32 cs = 0u, cd = 0u, ns = 0u, nd2 = 0u;
    uint4 G[4];                       // y fragments for tile t
    u16 prp[3]; float prpf[3];        // pos[src] for tile t (kgrp==3)
    float4 prpd = make_float4(0, 0, 0, 0);

    auto issueGather = [&](u32 src, u32 dst) {
        const u16* yp = y + (size_t)src * 128 + kgrp * 8;
#pragma unroll
        for (int f = 0; f < 4; f++) G[f] = *(const uint4*)(yp + f * 32);
        if (kgrp == 3) {
            if constexpr (BF16) {
                const u16* pp = (const u16*)pos;
#pragma unroll
                for (int c = 0; c < 3; c++) prp[c] = pp[(size_t)src * 3 + c];
            } else {
                const float* pp = (const float*)pos;
#pragma unroll
                for (int c = 0; c < 3; c++) prpf[c] = pp[(size_t)src * 3 + c];
            }
            prpd = pd4[dst];
        }
    };

    if (t < ntile) {
        long E = min((long)t * 16 + r16, (long)nE - 1);
        cs = ssrc[E]; cd = sdst[E];
        issueGather(cs, cd);
        int tn = t + stride;
        if (tn < ntile) {
            long En = min((long)tn * 16 + r16, (long)nE - 1);
            ns = ssrc[En]; nd2 = sdst[En];
        }
    }

    for (; t < ntile; t += stride) {
        asm volatile("" ::: "memory");
        // stage rel/dst for tile t (kgrp3 lanes; intra-wave DS in-order)
        if (kgrp == 3) {
            dstS[wid][r16] = (int)cd;
            float p0, p1, p2;
            if constexpr (BF16) { p0 = bf2f(prp[0]); p1 = bf2f(prp[1]); p2 = bf2f(prp[2]); }
            else                { p0 = prpf[0]; p1 = prpf[1]; p2 = prpf[2]; }
            relS[wid][r16 * 4 + 0] = p0 + prpd.x;
            relS[wid][r16 * 4 + 1] = p1 + prpd.y;
            relS[wid][r16 * 4 + 2] = p2 + prpd.z;
        }
        // neighbor dsts for boundary-run classification
        int dprevV = -1, dnextV = -1;
        {
            long e0 = (long)t * 16;
            if (e0 > 0) dprevV = (int)sdst[e0 - 1];
            if (e0 + 16 < (long)nE) dnextV = (int)sdst[e0 + 16];
        }
        float rl0 = relS[wid][r16 * 4 + 0];
        float rl1 = relS[wid][r16 * 4 + 1];
        float rl2 = relS[wid][r16 * 4 + 2];
        // ---- h fragments: relu(y + rel.w0r + b0), lane-local on its A-fragment slice ----
        bf16x8 hf[4];
#pragma unroll
        for (int f = 0; f < 4; f++) {
            u32 hw[4];
#pragma unroll
            for (int jj = 0; jj < 4; jj++) {
                int c0 = f * 32 + kgrp * 8 + 2 * jj;
                float4 wb0 = w0rb[c0];
                float4 wb1 = w0rb[c0 + 1];
                u32 pw = ((const u32*)&G[f])[jj];
                float y0 = bf2f((u16)(pw & 0xFFFF));
                float y1 = bf2f((u16)(pw >> 16));
                float h0 = fmaxf(y0 + rl0 * wb0.x + rl1 * wb0.y + rl2 * wb0.z + wb0.w, 0.f);
                float h1 = fmaxf(y1 + rl0 * wb1.x + rl1 * wb1.y + rl2 * wb1.z + wb1.w, 0.f);
                hw[jj] = (u32)f2bf(h0) | ((u32)f2bf(h1) << 16);
            }
            uint4 hv = make_uint4(hw[0], hw[1], hw[2], hw[3]);
            hf[f] = *(const bf16x8*)&hv;
        }
        // ---- G is dead: issue next tile's gathers + indices (depth-1 pipeline) ----
        u32 cs2 = ns, cd2 = nd2;
        {
            int tn = t + stride;
            if (tn < ntile) {
                issueGather(cs2, cd2);
                int tn2 = tn + stride;
                if (tn2 < ntile) {
                    long E2 = min((long)tn2 * 16 + r16, (long)nE - 1);
                    ns = ssrc[E2]; nd2 = sdst[E2];
                }
            }
        }
        // ---- GEMM2: e2 = h @ W1 (K=128, N=96), W1 from swizzled LDS ----
        f32x4 acc2[6];
#pragma unroll
        for (int nt = 0; nt < 6; nt++) {
#pragma unroll
            for (int r = 0; r < 4; r++) acc2[nt][r] = 0.f;
        }
#pragma unroll
        for (int nt = 0; nt < 6; nt++) {
            int colr = nt * 16 + r16;
            const char* wb = (const char*)w1S + colr * 256;
            int csw = (colr & 7) << 4;
            acc2[nt] = __builtin_amdgcn_mfma_f32_16x16x32_bf16(hf[0], *(const bf16x8*)(wb + ((kgrp * 16)       ^ csw)), acc2[nt], 0, 0, 0);
            acc2[nt] = __builtin_amdgcn_mfma_f32_16x16x32_bf16(hf[1], *(const bf16x8*)(wb + ((kgrp * 16 + 64)  ^ csw)), acc2[nt], 0, 0, 0);
            acc2[nt] = __builtin_amdgcn_mfma_f32_16x16x32_bf16(hf[2], *(const bf16x8*)(wb + ((kgrp * 16 + 128) ^ csw)), acc2[nt], 0, 0, 0);
            acc2[nt] = __builtin_amdgcn_mfma_f32_16x16x32_bf16(hf[3], *(const bf16x8*)(wb + ((kgrp * 16 + 192) ^ csw)), acc2[nt], 0, 0, 0);
        }
        // out (bf16) -> wave-local stride-98 overlay
#pragma unroll
        for (int nt = 0; nt < 6; nt++) {
            int col = nt * 16 + r16;
#pragma unroll
            for (int r = 0; r < 4; r++) {
                int row = kgrp * 4 + r;
                outSw[row * 98 + col] = f2bf(acc2[nt][r]);
            }
        }
        // ---- run-scan: plain stores (complete runs -> agg; boundary -> pbuf) ----
        {
            int d0s = dstS[wid][0], d15s = dstS[wid][15];
            bool extL = (dprevV == d0s);
            bool extR = (dnextV == d15s);
#pragma unroll
            for (int p = 0; p < 2; p++) {
                int col = p * 64 + lane;
                if (p == 0 || lane < 32) {
                    float b1c = b1s[col];
                    int curd = d0s;
                    int r0 = 0;
                    float m = bf2f(outSw[col]);
#pragma unroll
                    for (int row = 1; row < 16; row++) {
                        float v = bf2f(outSw[row * 98 + col]);
                        int d = dstS[wid][row];
                        if (d != curd) {
                            if (r0 == 0 && extL) pbuf[(size_t)t * 96 + col] = f2bf(m);
                            else agg[(size_t)curd * 96 + col] = f2bf(m + b1c);
                            curd = d; r0 = row; m = v;
                        } else m = fmaxf(m, v);
                    }
                    bool pl = (r0 == 0) && extL;
                    if (pl || extR) {
                        size_t slot = (r0 == 0) ? 0 : tailSlot;
                        pbuf[slot + (size_t)t * 96 + col] = f2bf(m);
                    } else agg[(size_t)curd * 96 + col] = f2bf(m + b1c);
                }
            }
        }
        cs = cs2; cd = cd2;
    }
}

// -------- K3: out = x + mlp_g(agg)  (96 -> 128 relu -> 96), MFMA; inline pbuf merge (ex-k_fixup) --------
template<int BF16>
__global__ __launch_bounds__(256)
void k_node(const void* __restrict__ x, const u16* __restrict__ agg,
            const u32* __restrict__ dstart, const u16* __restrict__ pbuf,
            const u16* __restrict__ w0tg, const u16* __restrict__ w1tg,
            const void* __restrict__ gb0, const void* __restrict__ gb1,
            const void* __restrict__ fb1,
            void* __restrict__ out, const u32* __restrict__ flags, int N, int nE)
{
    if (flags[0] != (u32)BF16) return;
    __shared__ __align__(16) char arena[32768];
    __shared__ float b0s[128];
    __shared__ float b1s[96];
    __shared__ float b1f[96];
    int tid = threadIdx.x;
    if (tid < 128) b0s[tid] = LD<BF16>(gb0, tid);
    if (tid < 96)  b1s[tid] = LD<BF16>(gb1, tid);
    if (tid < 96)  b1f[tid] = LD<BF16>(fb1, tid);
    __syncthreads();

    const int lane = tid & 63;
    const int wid  = tid >> 6;
    const int mrow0 = wid * 16;
    const int arow = mrow0 + (lane & 15);
    const int kgrp = lane >> 4;
    const int srow = tid >> 2;
    const int q = tid & 3;
    const int ssw = (srow & 7) << 4;
    const int ntileE = (nE + 15) / 16;

    float b0v[8];
#pragma unroll
    for (int nt = 0; nt < 8; nt++) b0v[nt] = b0s[nt * 16 + (lane & 15)];

    auto outOff = [](int row, int col) {
        int j = row & 15, w2 = row >> 4;
        int base = (j < 8) ? (w2 * 4096 + j * 512) : (16384 + w2 * 4096 + (j - 8) * 512);
        return base + ((col ^ (((row >> 2) & 3) << 4)) << 2);
    };

    int ntile = (N + 63) / 64;
    for (int t = blockIdx.x; t < ntile; t += gridDim.x) {
        asm volatile("" ::: "memory");
        {   // stage agg row: single-tile/empty -> agg; multi-tile -> merge pbuf partials (+fb1)
            int n = t * 64 + srow;
            if (n < N) {
                u32 s = dstart[n], e = dstart[n + 1];
                int t0 = (int)(s >> 4);
                int t1 = (e > s) ? (int)((e - 1) >> 4) : t0;
                if (e > s && t0 != t1) {
                    const u16* pH = pbuf;
                    const u16* pT = pbuf + (size_t)ntileE * 96;
                    const u16* first = ((s & 15u) == 0u) ? pH : pT;
#pragma unroll
                    for (int j = 0; j < 3; j++) {
                        int c = q * 3 + j;
                        float mf[8];
                        unpack8(first + (size_t)t0 * 96 + c * 8, mf);
                        for (int tt = t0 + 1; tt <= t1; tt++) {
                            float tf[8];
                            unpack8(pH + (size_t)tt * 96 + c * 8, tf);
#pragma unroll
                            for (int k = 0; k < 8; k++) mf[k] = fmaxf(mf[k], tf[k]);
                        }
                        u32 o[4];
#pragma unroll
                        for (int k = 0; k < 4; k++) {
                            u16 lo = f2bf(mf[2 * k]     + b1f[c * 8 + 2 * k]);
                            u16 hi = f2bf(mf[2 * k + 1] + b1f[c * 8 + 2 * k + 1]);
                            o[k] = (u32)lo | ((u32)hi << 16);
                        }
                        *(uint4*)(arena + srow * 256 + ((c * 16) ^ ssw)) = make_uint4(o[0], o[1], o[2], o[3]);
                    }
                } else {
                    const uint4* ar = (const uint4*)(agg + (size_t)n * 96);
#pragma unroll
                    for (int j = 0; j < 3; j++) {
                        int c = q * 3 + j;
                        *(uint4*)(arena + srow * 256 + ((c * 16) ^ ssw)) = ar[c];
                    }
                }
            } else {
#pragma unroll
                for (int j = 0; j < 3; j++)
                    *(uint4*)(arena + srow * 256 + (((q * 3 + j) * 16) ^ ssw)) = make_uint4(0u, 0u, 0u, 0u);
            }
        }
        __syncthreads();
        int sw = (arow & 7) << 4;
        bf16x8 a0 = *(const bf16x8*)(arena + arow * 256 + ((0   + kgrp * 16) ^ sw));
        bf16x8 a1 = *(const bf16x8*)(arena + arow * 256 + ((64  + kgrp * 16) ^ sw));
        bf16x8 a2 = *(const bf16x8*)(arena + arow * 256 + ((128 + kgrp * 16) ^ sw));
        f32x4 acc[8];
#pragma unroll
        for (int nt = 0; nt < 8; nt++) {
#pragma unroll
            for (int r = 0; r < 4; r++) acc[nt][r] = 0.f;
        }
#pragma unroll
        for (int nt = 0; nt < 8; nt++) {
            const u16* wp = w0tg + (long)(nt * 16 + (lane & 15)) * 128 + kgrp * 8;
            acc[nt] = __builtin_amdgcn_mfma_f32_16x16x32_bf16(a0, *(const bf16x8*)(wp),      acc[nt], 0, 0, 0);
            acc[nt] = __builtin_amdgcn_mfma_f32_16x16x32_bf16(a1, *(const bf16x8*)(wp + 32), acc[nt], 0, 0, 0);
            acc[nt] = __builtin_amdgcn_mfma_f32_16x16x32_bf16(a2, *(const bf16x8*)(wp + 64), acc[nt], 0, 0, 0);
        }
#pragma unroll
        for (int nt = 0; nt < 8; nt++) {
            int col = nt * 16 + (lane & 15);
#pragma unroll
            for (int r = 0; r < 4; r++) {
                int row = mrow0 + kgrp * 4 + r;
                float hv = fmaxf(acc[nt][r] + b0v[nt], 0.f);
                *(u16*)(arena + 16384 + row * 256 + ((col * 2) ^ ((row & 7) << 4))) = f2bf(hv);
            }
        }
        bf16x8 h0 = *(const bf16x8*)(arena + 16384 + arow * 256 + ((0   + kgrp * 16) ^ sw));
        bf16x8 h1 = *(const bf16x8*)(arena + 16384 + arow * 256 + ((64  + kgrp * 16) ^ sw));
        bf16x8 h2 = *(const bf16x8*)(arena + 16384 + arow * 256 + ((128 + kgrp * 16) ^ sw));
        bf16x8 h3 = *(const bf16x8*)(arena + 16384 + arow * 256 + ((192 + kgrp * 16) ^ sw));
        f32x4 acc2[6];
#pragma unroll
        for (int nt = 0; nt < 6; nt++) {
#pragma unroll
            for (int r = 0; r < 4; r++) acc2[nt][r] = 0.f;
        }
#pragma unroll
        for (int nt = 0; nt < 6; nt++) {
            const u16* wp = w1tg + (long)(nt * 16 + (lane & 15)) * 128 + kgrp * 8;
            acc2[nt] = __builtin_amdgcn_mfma_f32_16x16x32_bf16(h0, *(const bf16x8*)(wp),      acc2[nt], 0, 0, 0);
            acc2[nt] = __builtin_amdgcn_mfma_f32_16x16x32_bf16(h1, *(const bf16x8*)(wp + 32), acc2[nt], 0, 0, 0);
            acc2[nt] = __builtin_amdgcn_mfma_f32_16x16x32_bf16(h2, *(const bf16x8*)(wp + 64), acc2[nt], 0, 0, 0);
            acc2[nt] = __builtin_amdgcn_mfma_f32_16x16x32_bf16(h3, *(const bf16x8*)(wp + 96), acc2[nt], 0, 0, 0);
        }
#pragma unroll
        for (int nt = 0; nt < 6; nt++) {
            int col = nt * 16 + (lane & 15);
#pragma unroll
            for (int r = 0; r < 4; r++) {
                int row = mrow0 + kgrp * 4 + r;
                *(float*)(arena + outOff(row, col)) = acc2[nt][r];
            }
        }
        __syncthreads();
        {
            int n = t * 64 + srow;
            if (n < N) {
                float v[24];
#pragma unroll
                for (int c = 0; c < 24; c++) v[c] = *(const float*)(arena + outOff(srow, q * 24 + c));
                if constexpr (BF16) {
                    u16* orow = (u16*)out + (size_t)n * 96 + q * 24;
#pragma unroll
                    for (int j = 0; j < 3; j++) {
                        float xv[8];
                        unpack8((const u16*)x + (size_t)n * 96 + q * 24 + j * 8, xv);
                        u32 o[4];
#pragma unroll
                        for (int c2 = 0; c2 < 4; c2++) {
                            int c = j * 8 + 2 * c2;
                            u16 lo = f2bf(xv[2 * c2]     + v[c]     + b1s[q * 24 + c]);
                            u16 hi = f2bf(xv[2 * c2 + 1] + v[c + 1] + b1s[q * 24 + c + 1]);
                            o[c2] = (u32)lo | ((u32)hi << 16);
                        }
                        *(uint4*)(orow + j * 8) = make_uint4(o[0], o[1], o[2], o[3]);
                    }
                } else {
                    const float* xr = (const float*)x + (size_t)n * 96 + q * 24;
                    float* orow = (float*)out + (size_t)n * 96 + q * 24;
#pragma unroll
                    for (int j = 0; j < 6; j++) {
                        float4 xv = ((const float4*)xr)[j];
                        float4 o;
                        o.x = xv.x + v[4 * j + 0] + b1s[q * 24 + 4 * j + 0];
                        o.y = xv.y + v[4 * j + 1] + b1s[q * 24 + 4 * j + 1];
                        o.z = xv.z + v[4 * j + 2] + b1s[q * 24 + 4 * j + 2];
                        o.w = xv.w + v[4 * j + 3] + b1s[q * 24 + 4 * j + 3];
                        ((float4*)orow)[j] = o;
                    }
                }
            }
        }
        __syncthreads();
    }
}

extern "C" void kernel_launch(void* const* d_in, const int* in_sizes, int n_in,
                              void* d_out, int out_size, void* d_ws, size_t ws_size,
                              hipStream_t stream) {
    const void* x   = d_in[0];
    const void* pos = d_in[1];
    const void* ei  = d_in[2];
    const void* hw0 = d_in[3];
    const void* hb0 = d_in[4];
    const void* hw1 = d_in[5];
    const void* hb1 = d_in[6];
    const void* fw0 = d_in[7];
    const void* fb0 = d_in[8];
    const void* fw1 = d_in[9];
    const void* fb1 = d_in[10];
    const void* gw0 = d_in[11];
    const void* gb0 = d_in[12];
    const void* gw1 = d_in[13];
    const void* gb1 = d_in[14];

    int N  = in_sizes[0] / 96;   // 50000
    int nE = in_sizes[2] / 2;    // 800000
    int ntileE = (nE + 15) / 16; // 50000

    // workspace layout (256B aligned), total ~50 MB
    size_t off = 0;
    auto alloc = [&](size_t bytes) { size_t o = off; off = (off + bytes + 255) & ~(size_t)255; return o; };
    u32*    flags    = (u32*)((char*)d_ws + alloc(256));
    float4* pd4      = (float4*)((char*)d_ws + alloc((size_t)N * 16));
    u16*    w0t      = (u16*)((char*)d_ws + alloc(128 * 128 * 2));
    u16*    w1t      = (u16*)((char*)d_ws + alloc(96 * 128 * 2));
    u16*    w0tg     = (u16*)((char*)d_ws + alloc(128 * 128 * 2));
    u16*    w1tg     = (u16*)((char*)d_ws + alloc(96 * 128 * 2));
    u32*    binCur   = (u32*)((char*)d_ws + alloc((size_t)N * 4));
    u32*    dstStart = (u32*)((char*)d_ws + alloc((size_t)(N + 1) * 4));
    u16*    agg      = (u16*)((char*)d_ws + alloc((size_t)N * 96 * 2));
    u32*    ssrc     = (u32*)((char*)d_ws + alloc((size_t)nE * 4));
    u32*    sdst     = (u32*)((char*)d_ws + alloc((size_t)nE * 4));
    u16*    pbuf     = (u16*)((char*)d_ws + alloc((size_t)2 * ntileE * 96 * 2));
    u16*    ybuf     = (u16*)((char*)d_ws + alloc((size_t)N * 128 * 2));

    k_detect<<<1, 64, 0, stream>>>((const u32*)x, (const u32*)ei, flags);
    k_initall<<<1024, 256, 0, stream>>>((u32*)agg, N * 96 / 2, binCur, N);
    k_prep<<<64, 256, 0, stream>>>(fw0, fw1, w0t, w1t, flags, 3);
    k_prep<<<64, 256, 0, stream>>>(gw0, gw1, w0tg, w1tg, flags, 0);
    k_hist<<<1024, 256, 0, stream>>>((const u32*)ei, binCur, flags, nE, N);
    k_scan<<<1, 1024, 0, stream>>>(binCur, dstStart, N, (u32)nE);
    k_scatter<<<1024, 256, 0, stream>>>((const u32*)ei, binCur, ssrc, sdst, flags, nE, N);
    k_delta<1><<<(N + 255) / 256, 256, 0, stream>>>(x, pos, hw0, hb0, hw1, hb1, pd4, flags, N);
    k_delta<0><<<(N + 255) / 256, 256, 0, stream>>>(x, pos, hw0, hb0, hw1, hb1, pd4, flags, N);
    int yGrid = (N + 63) / 64;
    k_y<1><<<yGrid, 256, 0, stream>>>(x, w0t, ybuf, flags, N);
    k_y<0><<<yGrid, 256, 0, stream>>>(x, w0t, ybuf, flags, N);
    k_edge<1><<<1024, 256, 0, stream>>>(ybuf, pos, pd4, ssrc, sdst, w1t, fw0, fb0, fb1, flags, agg, pbuf, nE, N);
    k_edge<0><<<1024, 256, 0, stream>>>(ybuf, pos, pd4, ssrc, sdst, w1t, fw0, fb0, fb1, flags, agg, pbuf, nE, N);
    int nodeGrid = (N + 63) / 64;
    k_node<1><<<nodeGrid, 256, 0, stream>>>(x, agg, dstStart, pbuf, w0tg, w1tg, gb0, gb1, fb1, d_out, flags, N, nE);
    k_node<0><<<nodeGrid, 256, 0, stream>>>(x, agg, dstStart, pbuf, w0tg, w1tg, gb0, gb1, fb1, d_out, flags, N, nE);
}